// Round 1
// baseline (1939.014 us; speedup 1.0000x reference)
//
#include <hip/hip_runtime.h>
#include <math.h>

#define DEV __device__ __forceinline__

DEV unsigned enc_f(float f) {
    unsigned u = __float_as_uint(f);
    return (u & 0x80000000u) ? ~u : (u | 0x80000000u);
}
DEV float dec_f(unsigned k) {
    return (k & 0x80000000u) ? __uint_as_float(k ^ 0x80000000u)
                             : __uint_as_float(~k);
}

// ---------------- init kernels ----------------
__global__ void k_init(float* acc, int accN, unsigned* m, float* den, int N,
                       float* pooled, float* counts, int PN) {
    int i = blockIdx.x * blockDim.x + threadIdx.x;
    int stride = gridDim.x * blockDim.x;
    for (int j = i; j < accN; j += stride) acc[j] = 0.f;
    for (int j = i; j < N; j += stride) { m[j] = 0x007FFFFFu; den[j] = 0.f; }
    if (pooled) for (int j = i; j < PN; j += stride) pooled[j] = 0.f;
    if (counts) for (int j = i; j < PN / 32 + 1; j += stride)
        if (j < (PN >> 5)) counts[j] = 0.f;
}

// ---------------- layer 1: node transforms 17 -> 128 ----------------
__global__ void k_xform1(const float* __restrict__ x,
                         const float* __restrict__ Wl, const float* __restrict__ bl,
                         const float* __restrict__ Wr, const float* __restrict__ br,
                         float* __restrict__ xl, float* __restrict__ xr, int N) {
    __shared__ float xrow[17];
    int n = blockIdx.x;
    int d = threadIdx.x;  // 128 threads
    if (d < 17) xrow[d] = x[(size_t)n * 17 + d];
    __syncthreads();
    float a = bl[d], b = br[d];
#pragma unroll
    for (int k = 0; k < 17; k++) {
        float xv = xrow[k];
        a += xv * Wl[k * 128 + d];
        b += xv * Wr[k * 128 + d];
    }
    xl[(size_t)n * 128 + d] = a;
    xr[(size_t)n * 128 + d] = b;
}

// ---------------- layer 1: edge scores + segment max (D=128) ----------------
__global__ void k_score1(const int* __restrict__ ei, int E, int ET,
                         const float* __restrict__ xl, const float* __restrict__ xr,
                         const float* __restrict__ att,
                         float* __restrict__ sc, unsigned* __restrict__ m) {
    int w = (blockIdx.x * blockDim.x + threadIdx.x) >> 6;
    int lane = threadIdx.x & 63;
    if (w >= ET) return;
    int src = (w < E) ? ei[w] : (w - E);
    int dst = (w < E) ? ei[E + w] : (w - E);
    const float* pl = xl + (size_t)src * 128;
    const float* pr = xr + (size_t)dst * 128;
    float v0 = pl[lane] + pr[lane];
    float v1 = pl[lane + 64] + pr[lane + 64];
    v0 = (v0 > 0.f) ? v0 : 0.2f * v0;
    v1 = (v1 > 0.f) ? v1 : 0.2f * v1;
    float p = v0 * att[lane] + v1 * att[lane + 64];
#pragma unroll
    for (int o = 32; o >= 1; o >>= 1) p += __shfl_xor(p, o);
    if (lane == 0) {
        sc[w] = p;
        atomicMax(m + dst, enc_f(p));
    }
}

// ---------------- layer 1: exp + denom + weighted scatter (D=128) ----------------
__global__ void k_scatter1(const int* __restrict__ ei, int E, int ET,
                           const float* __restrict__ xl,
                           const float* __restrict__ sc, const unsigned* __restrict__ m,
                           float* __restrict__ den, float* __restrict__ acc) {
    int w = (blockIdx.x * blockDim.x + threadIdx.x) >> 6;
    int lane = threadIdx.x & 63;
    if (w >= ET) return;
    int src = (w < E) ? ei[w] : (w - E);
    int dst = (w < E) ? ei[E + w] : (w - E);
    float ex = expf(sc[w] - dec_f(m[dst]));
    if (lane == 0) atomicAdd(den + dst, ex);
    const float* pl = xl + (size_t)src * 128;
    float* pa = acc + (size_t)dst * 128;
    atomicAdd(pa + lane, ex * pl[lane]);
    atomicAdd(pa + lane + 64, ex * pl[lane + 64]);
}

// ---------------- layer 1: finalize (divide + bias + elu), in place ----------------
__global__ void k_fin1(float* __restrict__ acc, const float* __restrict__ den,
                       const float* __restrict__ bias, int N) {
    int tot = N * 128;
    int stride = gridDim.x * blockDim.x;
    for (int i = blockIdx.x * blockDim.x + threadIdx.x; i < tot; i += stride) {
        int n = i >> 7;
        int d = i & 127;
        float v = acc[i] / (den[n] + 1e-16f) + bias[d];
        acc[i] = (v > 0.f) ? v : expm1f(v);
    }
}

// ---------------- layer 2: node transforms 128 -> 32 ----------------
__global__ void k_xform2(const float* __restrict__ h,
                         const float* __restrict__ Wl, const float* __restrict__ bl,
                         const float* __restrict__ Wr, const float* __restrict__ br,
                         float* __restrict__ xl2, float* __restrict__ xr2, int N) {
    __shared__ float hrow[128];
    int n = blockIdx.x;
    int t = threadIdx.x;  // 64 threads
    hrow[t] = h[(size_t)n * 128 + t];
    hrow[t + 64] = h[(size_t)n * 128 + t + 64];
    __syncthreads();
    if (t < 32) {
        float a = bl[t];
#pragma unroll
        for (int k = 0; k < 128; k++) a += hrow[k] * Wl[k * 32 + t];
        xl2[(size_t)n * 32 + t] = a;
    } else {
        int d = t - 32;
        float b = br[d];
#pragma unroll
        for (int k = 0; k < 128; k++) b += hrow[k] * Wr[k * 32 + d];
        xr2[(size_t)n * 32 + d] = b;
    }
}

// ---------------- layer 2: edge scores + segment max (D=32) ----------------
__global__ void k_score2(const int* __restrict__ ei, int E, int ET,
                         const float* __restrict__ xl, const float* __restrict__ xr,
                         const float* __restrict__ att,
                         float* __restrict__ sc, unsigned* __restrict__ m) {
    int w = (blockIdx.x * blockDim.x + threadIdx.x) >> 6;
    int lane = threadIdx.x & 63;
    if (w >= ET) return;
    int src = (w < E) ? ei[w] : (w - E);
    int dst = (w < E) ? ei[E + w] : (w - E);
    float p = 0.f;
    if (lane < 32) {
        float v = xl[(size_t)src * 32 + lane] + xr[(size_t)dst * 32 + lane];
        v = (v > 0.f) ? v : 0.2f * v;
        p = v * att[lane];
    }
#pragma unroll
    for (int o = 32; o >= 1; o >>= 1) p += __shfl_xor(p, o);
    if (lane == 0) {
        sc[w] = p;
        atomicMax(m + dst, enc_f(p));
    }
}

// ---------------- layer 2: exp + denom + weighted scatter (D=32) ----------------
__global__ void k_scatter2(const int* __restrict__ ei, int E, int ET,
                           const float* __restrict__ xl,
                           const float* __restrict__ sc, const unsigned* __restrict__ m,
                           float* __restrict__ den, float* __restrict__ acc) {
    int w = (blockIdx.x * blockDim.x + threadIdx.x) >> 6;
    int lane = threadIdx.x & 63;
    if (w >= ET) return;
    int src = (w < E) ? ei[w] : (w - E);
    int dst = (w < E) ? ei[E + w] : (w - E);
    float ex = expf(sc[w] - dec_f(m[dst]));
    if (lane == 0) atomicAdd(den + dst, ex);
    if (lane < 32)
        atomicAdd(acc + (size_t)dst * 32 + lane, ex * xl[(size_t)src * 32 + lane]);
}

// ---------------- layer 2 finalize + mean-pool accumulate ----------------
__global__ void k_fin2_pool(const float* __restrict__ acc, const float* __restrict__ den,
                            const float* __restrict__ bias, const int* __restrict__ batch,
                            float* __restrict__ pooled, float* __restrict__ counts, int N) {
    int tot = N * 32;
    int stride = gridDim.x * blockDim.x;
    for (int i = blockIdx.x * blockDim.x + threadIdx.x; i < tot; i += stride) {
        int n = i >> 5;
        int d = i & 31;
        float v = acc[i] / (den[n] + 1e-16f) + bias[d];
        v = (v > 0.f) ? v : expm1f(v);
        int g = batch[n];
        atomicAdd(pooled + g * 32 + d, v);
        if (d == 0) atomicAdd(counts + g, 1.0f);
    }
}

// ---------------- head: obs/noise encoders + fusion MLP ----------------
__global__ void k_head(const float* __restrict__ pooled, const float* __restrict__ counts,
                       const float* __restrict__ obs, const float* __restrict__ nf,
                       const float* __restrict__ ne,
                       const float* __restrict__ Wo1, const float* __restrict__ bo1,
                       const float* __restrict__ Wo2, const float* __restrict__ bo2,
                       const float* __restrict__ Wn, const float* __restrict__ bn,
                       const float* __restrict__ Wf1, const float* __restrict__ bf1,
                       const float* __restrict__ Wf2, const float* __restrict__ bf2,
                       const float* __restrict__ Wf3, const float* __restrict__ bf3,
                       float* __restrict__ out) {
    __shared__ float comb[45];
    __shared__ float ho[32];
    __shared__ float h1[256];
    __shared__ float h2[32];
    int g = blockIdx.x;
    int t = threadIdx.x;  // 256 threads
    if (t < 32) {
        float c = counts[g];
        c = (c > 1.f) ? c : 1.f;
        comb[t] = pooled[g * 32 + t] / c;
        float a = bo1[t];
#pragma unroll
        for (int k = 0; k < 5; k++) a += obs[g * 5 + k] * Wo1[k * 32 + t];
        ho[t] = (a > 0.f) ? a : 0.f;
    }
    __syncthreads();
    if (t < 8) {
        float a = bo2[t];
#pragma unroll
        for (int k = 0; k < 32; k++) a += ho[k] * Wo2[k * 8 + t];
        comb[32 + t] = a;
    }
    if (t >= 8 && t < 12) {
        int d = t - 8;
        comb[40 + d] = nf[g] * Wn[d] + bn[d];
    }
    if (t == 12) comb[44] = ne[g];
    __syncthreads();
    {
        float a = bf1[t];
#pragma unroll
        for (int k = 0; k < 45; k++) a += comb[k] * Wf1[k * 256 + t];
        h1[t] = (a > 0.f) ? a : 0.f;
    }
    __syncthreads();
    if (t < 32) {
        float a = bf2[t];
#pragma unroll
        for (int k = 0; k < 256; k++) a += h1[k] * Wf2[k * 32 + t];
        h2[t] = (a > 0.f) ? a : 0.f;
    }
    __syncthreads();
    if (t == 0) {
        float a = bf3[0];
#pragma unroll
        for (int k = 0; k < 32; k++) a += h2[k] * Wf3[k];
        out[g] = ne[g] + a;
    }
}

extern "C" void kernel_launch(void* const* d_in, const int* in_sizes, int n_in,
                              void* d_out, int out_size, void* d_ws, size_t ws_size,
                              hipStream_t stream) {
    const float* x = (const float*)d_in[0];
    const int* ei = (const int*)d_in[1];
    const int* batch = (const int*)d_in[2];
    const float* obs = (const float*)d_in[3];
    const float* nf = (const float*)d_in[4];
    const float* ne = (const float*)d_in[5];
    const float* Wl1 = (const float*)d_in[6];
    const float* bl1 = (const float*)d_in[7];
    const float* Wr1 = (const float*)d_in[8];
    const float* br1 = (const float*)d_in[9];
    const float* att1 = (const float*)d_in[10];
    const float* bias1 = (const float*)d_in[11];
    const float* Wl2 = (const float*)d_in[12];
    const float* bl2 = (const float*)d_in[13];
    const float* Wr2 = (const float*)d_in[14];
    const float* br2 = (const float*)d_in[15];
    const float* att2 = (const float*)d_in[16];
    const float* bias2 = (const float*)d_in[17];
    const float* Wo1 = (const float*)d_in[18];
    const float* bo1 = (const float*)d_in[19];
    const float* Wo2 = (const float*)d_in[20];
    const float* bo2 = (const float*)d_in[21];
    const float* Wn = (const float*)d_in[22];
    const float* bn = (const float*)d_in[23];
    const float* Wf1 = (const float*)d_in[24];
    const float* bf1 = (const float*)d_in[25];
    const float* Wf2 = (const float*)d_in[26];
    const float* bf2 = (const float*)d_in[27];
    const float* Wf3 = (const float*)d_in[28];
    const float* bf3 = (const float*)d_in[29];

    const int N = in_sizes[0] / 17;
    const int E = in_sizes[1] / 2;
    const int G = in_sizes[3] / 5;
    const int ET = E + N;

    float* ws = (float*)d_ws;
    size_t o = 0;
    float* xl1 = ws + o; o += (size_t)N * 128;
    float* xr1 = ws + o; o += (size_t)N * 128;
    float* acc1 = ws + o; o += (size_t)N * 128;   // becomes h1 after fin1
    float* sc = ws + o; o += (size_t)ET;
    unsigned* m = (unsigned*)(ws + o); o += N;
    float* den = ws + o; o += N;
    float* pooled = ws + o; o += (size_t)G * 32;
    float* counts = ws + o; o += G;
    // layer-2 buffers alias the (dead by then) xl1 region
    float* xl2 = xl1;
    float* xr2 = xl1 + (size_t)N * 32;
    float* acc2 = xl1 + (size_t)2 * N * 32;

    const int edgeBlocks = (ET * 64 + 255) / 256;

    // ---- layer 1 ----
    k_init<<<2048, 256, 0, stream>>>(acc1, N * 128, m, den, N, nullptr, nullptr, 0);
    k_xform1<<<N, 128, 0, stream>>>(x, Wl1, bl1, Wr1, br1, xl1, xr1, N);
    k_score1<<<edgeBlocks, 256, 0, stream>>>(ei, E, ET, xl1, xr1, att1, sc, m);
    k_scatter1<<<edgeBlocks, 256, 0, stream>>>(ei, E, ET, xl1, sc, m, den, acc1);
    k_fin1<<<2048, 256, 0, stream>>>(acc1, den, bias1, N);

    // ---- layer 2 ----
    k_xform2<<<N, 64, 0, stream>>>(acc1, Wl2, bl2, Wr2, br2, xl2, xr2, N);
    k_init<<<1024, 256, 0, stream>>>(acc2, N * 32, m, den, N, pooled, counts, G * 32);
    k_score2<<<edgeBlocks, 256, 0, stream>>>(ei, E, ET, xl2, xr2, att2, sc, m);
    k_scatter2<<<edgeBlocks, 256, 0, stream>>>(ei, E, ET, xl2, sc, m, den, acc2);
    k_fin2_pool<<<1024, 256, 0, stream>>>(acc2, den, bias2, batch, pooled, counts, N);

    // ---- head ----
    k_head<<<G, 256, 0, stream>>>(pooled, counts, obs, nf, ne,
                                  Wo1, bo1, Wo2, bo2, Wn, bn,
                                  Wf1, bf1, Wf2, bf2, Wf3, bf3,
                                  (float*)d_out);
}

// Round 2
// 398.124 us; speedup vs baseline: 4.8704x; 4.8704x over previous
//
#include <hip/hip_runtime.h>
#include <math.h>

// ---------------- utility: zero ints ----------------
__global__ void k_zero_i(int* a, int n) {
    int i = blockIdx.x * blockDim.x + threadIdx.x;
    int s = gridDim.x * blockDim.x;
    for (; i < n; i += s) a[i] = 0;
}

// ---------------- CSR build ----------------
__global__ void k_hist(const int* __restrict__ ei, int E, int ET, int* __restrict__ deg) {
    int e = blockIdx.x * blockDim.x + threadIdx.x;
    if (e >= ET) return;
    int dst = (e < E) ? ei[E + e] : (e - E);
    atomicAdd(deg + dst, 1);
}

#define SCH 1024
__global__ void k_scan1(const int* __restrict__ deg, int N, int* __restrict__ rowptr,
                        int* __restrict__ part) {
    __shared__ int s[SCH];
    int b = blockIdx.x, t = threadIdx.x;
    int gi = b * SCH + t;
    s[t] = (gi < N) ? deg[gi] : 0;
    __syncthreads();
    for (int o = 1; o < SCH; o <<= 1) {
        int add = (t >= o) ? s[t - o] : 0;
        __syncthreads();
        s[t] += add;
        __syncthreads();
    }
    if (gi < N) rowptr[gi + 1] = s[t];
    if (t == SCH - 1) part[b] = s[t];
}

__global__ void k_scan2(int* part, int nb) {
    if (threadIdx.x == 0) {
        int r = 0;
        for (int i = 0; i < nb; i++) { r += part[i]; part[i] = r; }
    }
}

__global__ void k_scan3(int* __restrict__ rowptr, const int* __restrict__ part, int N,
                        int* __restrict__ cursor) {
    int b = blockIdx.x, t = threadIdx.x;
    int gi = b * SCH + t;
    if (gi < N) {
        if (b > 0) rowptr[gi + 1] += part[b - 1];
        cursor[gi] = 0;
    }
    if (b == 0 && t == 0) rowptr[0] = 0;
}

__global__ void k_fill(const int* __restrict__ ei, int E, int ET,
                       const int* __restrict__ rowptr, int* __restrict__ cursor,
                       int* __restrict__ srcs) {
    int e = blockIdx.x * blockDim.x + threadIdx.x;
    if (e >= ET) return;
    int src = (e < E) ? ei[e] : (e - E);
    int dst = (e < E) ? ei[E + e] : (e - E);
    int slot = rowptr[dst] + atomicAdd(cursor + dst, 1);
    srcs[slot] = src;
}

// ---------------- layer 1 transform: 17 -> 128, weight-stationary ----------------
__global__ void k_xform1(const float* __restrict__ x,
                         const float* __restrict__ Wl, const float* __restrict__ bl,
                         const float* __restrict__ Wr, const float* __restrict__ br,
                         float* __restrict__ xl, float* __restrict__ xr, int N) {
    __shared__ float wl[17 * 128], wr[17 * 128], sbl[128], sbr[128];
    int t = threadIdx.x;  // 256
    for (int i = t; i < 17 * 128; i += 256) { wl[i] = Wl[i]; wr[i] = Wr[i]; }
    if (t < 128) { sbl[t] = bl[t]; sbr[t] = br[t]; }
    __syncthreads();
    int wid = (blockIdx.x * 256 + t) >> 6;
    int lane = t & 63;
    int nw = gridDim.x * 4;
    for (int n = wid; n < N; n += nw) {
        float xv[17];
#pragma unroll
        for (int k = 0; k < 17; k++) xv[k] = x[n * 17 + k];
        float a0 = sbl[lane], a1 = sbl[lane + 64];
        float b0 = sbr[lane], b1 = sbr[lane + 64];
#pragma unroll
        for (int k = 0; k < 17; k++) {
            float xk = xv[k];
            a0 += xk * wl[k * 128 + lane];
            a1 += xk * wl[k * 128 + 64 + lane];
            b0 += xk * wr[k * 128 + lane];
            b1 += xk * wr[k * 128 + 64 + lane];
        }
        xl[n * 128 + lane] = a0; xl[n * 128 + 64 + lane] = a1;
        xr[n * 128 + lane] = b0; xr[n * 128 + 64 + lane] = b1;
    }
}

// ---------------- layer 1 aggregate: one wave per dst, online softmax ----------------
__global__ void k_agg1(const int* __restrict__ rowptr, const int* __restrict__ srcs,
                       const float* __restrict__ xl, const float* __restrict__ xr,
                       const float* __restrict__ att, const float* __restrict__ bias,
                       float* __restrict__ h1, int N) {
    int w = (blockIdx.x * blockDim.x + threadIdx.x) >> 6;
    int lane = threadIdx.x & 63;
    if (w >= N) return;
    float r0 = xr[w * 128 + lane], r1 = xr[w * 128 + 64 + lane];
    float a0 = att[lane], a1 = att[lane + 64];
    float m = -INFINITY, den = 0.f, acc0 = 0.f, acc1 = 0.f;
    int jb = rowptr[w], je = rowptr[w + 1];
    for (int j = jb; j < je; j++) {
        int src = srcs[j];
        float l0 = xl[src * 128 + lane], l1 = xl[src * 128 + 64 + lane];
        float v0 = l0 + r0; v0 = (v0 > 0.f) ? v0 : 0.2f * v0;
        float v1 = l1 + r1; v1 = (v1 > 0.f) ? v1 : 0.2f * v1;
        float p = v0 * a0 + v1 * a1;
#pragma unroll
        for (int o = 32; o; o >>= 1) p += __shfl_xor(p, o);
        if (p > m) {
            float s = __expf(m - p);
            den *= s; acc0 *= s; acc1 *= s; m = p;
        }
        float e = __expf(p - m);
        den += e; acc0 += e * l0; acc1 += e * l1;
    }
    float inv = 1.f / (den + 1e-16f);
    float o0 = acc0 * inv + bias[lane];
    float o1 = acc1 * inv + bias[lane + 64];
    h1[w * 128 + lane] = (o0 > 0.f) ? o0 : expm1f(o0);
    h1[w * 128 + 64 + lane] = (o1 > 0.f) ? o1 : expm1f(o1);
}

// ---------------- layer 2 transform: 128 -> 32, weight-stationary ----------------
__global__ void k_xform2(const float* __restrict__ h,
                         const float* __restrict__ Wl, const float* __restrict__ bl,
                         const float* __restrict__ Wr, const float* __restrict__ br,
                         float* __restrict__ xl2, float* __restrict__ xr2, int N) {
    __shared__ float wl[128 * 32], wr[128 * 32], sb[64];
    int t = threadIdx.x;  // 256
    for (int i = t; i < 128 * 32; i += 256) { wl[i] = Wl[i]; wr[i] = Wr[i]; }
    if (t < 32) sb[t] = bl[t];
    else if (t < 64) sb[t] = br[t - 32];
    __syncthreads();
    int wid = (blockIdx.x * 256 + t) >> 6;
    int lane = t & 63;
    int half = lane >> 5, d = lane & 31;
    const float* w = half ? wr : wl;
    float* o = half ? xr2 : xl2;
    float bb = sb[half * 32 + d];
    int nw = gridDim.x * 4;
    for (int n = wid; n < N; n += nw) {
        const float* hr = h + n * 128;
        float a = bb;
#pragma unroll 8
        for (int k = 0; k < 128; k++) a += hr[k] * w[k * 32 + d];
        o[n * 32 + d] = a;
    }
}

// ---------------- layer 2 aggregate: half-wave per dst, online softmax ----------------
__global__ void k_agg2(const int* __restrict__ rowptr, const int* __restrict__ srcs,
                       const float* __restrict__ xl, const float* __restrict__ xr,
                       const float* __restrict__ att, const float* __restrict__ bias,
                       float* __restrict__ h2, int N) {
    int w = (blockIdx.x * blockDim.x + threadIdx.x) >> 6;
    int lane = threadIdx.x & 63;
    int half = lane >> 5, d = lane & 31;
    int node = w * 2 + half;
    if (node >= N) return;
    float r = xr[node * 32 + d], a = att[d];
    float m = -INFINITY, den = 0.f, acc = 0.f;
    int jb = rowptr[node], je = rowptr[node + 1];
    for (int j = jb; j < je; j++) {
        int src = srcs[j];
        float l = xl[src * 32 + d];
        float v = l + r; v = (v > 0.f) ? v : 0.2f * v;
        float p = v * a;
#pragma unroll
        for (int o = 16; o; o >>= 1) p += __shfl_xor(p, o, 32);
        if (p > m) {
            float s = __expf(m - p);
            den *= s; acc *= s; m = p;
        }
        float e = __expf(p - m);
        den += e; acc += e * l;
    }
    float ov = acc / (den + 1e-16f) + bias[d];
    h2[node * 32 + d] = (ov > 0.f) ? ov : expm1f(ov);
}

// ---------------- graph bounds (batch is sorted) ----------------
__global__ void k_bounds(const int* __restrict__ batch, int N, int G, int* __restrict__ gb) {
    int g = blockIdx.x * blockDim.x + threadIdx.x;
    if (g > G) return;
    if (g == G) { gb[G] = N; return; }
    int lo = 0, hi = N;
    while (lo < hi) {
        int mid = (lo + hi) >> 1;
        if (batch[mid] < g) lo = mid + 1; else hi = mid;
    }
    gb[g] = lo;
}

// ---------------- head: pool + encoders + fusion MLP ----------------
__global__ void k_head(const float* __restrict__ h2, const int* __restrict__ gb,
                       const float* __restrict__ obs, const float* __restrict__ nf,
                       const float* __restrict__ ne,
                       const float* __restrict__ Wo1, const float* __restrict__ bo1,
                       const float* __restrict__ Wo2, const float* __restrict__ bo2,
                       const float* __restrict__ Wn, const float* __restrict__ bn,
                       const float* __restrict__ Wf1, const float* __restrict__ bf1,
                       const float* __restrict__ Wf2, const float* __restrict__ bf2,
                       const float* __restrict__ Wf3, const float* __restrict__ bf3,
                       float* __restrict__ out) {
    __shared__ float red[8][33];
    __shared__ float comb[45];
    __shared__ float ho[32];
    __shared__ float hh1[256];
    __shared__ float hh2[32];
    int g = blockIdx.x;
    int t = threadIdx.x;  // 256
    int s0 = gb[g], s1 = gb[g + 1];
    int d = t & 31, sub = t >> 5;
    float loc = 0.f;
    for (int n = s0 + sub; n < s1; n += 8) loc += h2[n * 32 + d];
    red[sub][d] = loc;
    __syncthreads();
    if (t < 32) {
        float sum = 0.f;
#pragma unroll
        for (int i = 0; i < 8; i++) sum += red[i][t];
        float c = (float)(s1 - s0);
        c = (c > 1.f) ? c : 1.f;
        comb[t] = sum / c;
        float a = bo1[t];
#pragma unroll
        for (int k = 0; k < 5; k++) a += obs[g * 5 + k] * Wo1[k * 32 + t];
        ho[t] = (a > 0.f) ? a : 0.f;
    }
    __syncthreads();
    if (t < 8) {
        float a = bo2[t];
#pragma unroll
        for (int k = 0; k < 32; k++) a += ho[k] * Wo2[k * 8 + t];
        comb[32 + t] = a;
    }
    if (t >= 8 && t < 12) {
        int dd = t - 8;
        comb[40 + dd] = nf[g] * Wn[dd] + bn[dd];
    }
    if (t == 12) comb[44] = ne[g];
    __syncthreads();
    {
        float a = bf1[t];
#pragma unroll
        for (int k = 0; k < 45; k++) a += comb[k] * Wf1[k * 256 + t];
        hh1[t] = (a > 0.f) ? a : 0.f;
    }
    __syncthreads();
    if (t < 32) {
        float a = bf2[t];
#pragma unroll
        for (int k = 0; k < 256; k++) a += hh1[k] * Wf2[k * 32 + t];
        hh2[t] = (a > 0.f) ? a : 0.f;
    }
    __syncthreads();
    if (t == 0) {
        float a = bf3[0];
#pragma unroll
        for (int k = 0; k < 32; k++) a += hh2[k] * Wf3[k];
        out[g] = ne[g] + a;
    }
}

extern "C" void kernel_launch(void* const* d_in, const int* in_sizes, int n_in,
                              void* d_out, int out_size, void* d_ws, size_t ws_size,
                              hipStream_t stream) {
    const float* x = (const float*)d_in[0];
    const int* ei = (const int*)d_in[1];
    const int* batch = (const int*)d_in[2];
    const float* obs = (const float*)d_in[3];
    const float* nf = (const float*)d_in[4];
    const float* ne = (const float*)d_in[5];
    const float* Wl1 = (const float*)d_in[6];
    const float* bl1 = (const float*)d_in[7];
    const float* Wr1 = (const float*)d_in[8];
    const float* br1 = (const float*)d_in[9];
    const float* att1 = (const float*)d_in[10];
    const float* bias1 = (const float*)d_in[11];
    const float* Wl2 = (const float*)d_in[12];
    const float* bl2 = (const float*)d_in[13];
    const float* Wr2 = (const float*)d_in[14];
    const float* br2 = (const float*)d_in[15];
    const float* att2 = (const float*)d_in[16];
    const float* bias2 = (const float*)d_in[17];
    const float* Wo1 = (const float*)d_in[18];
    const float* bo1 = (const float*)d_in[19];
    const float* Wo2 = (const float*)d_in[20];
    const float* bo2 = (const float*)d_in[21];
    const float* Wn = (const float*)d_in[22];
    const float* bn = (const float*)d_in[23];
    const float* Wf1 = (const float*)d_in[24];
    const float* bf1 = (const float*)d_in[25];
    const float* Wf2 = (const float*)d_in[26];
    const float* bf2 = (const float*)d_in[27];
    const float* Wf3 = (const float*)d_in[28];
    const float* bf3 = (const float*)d_in[29];

    const int N = in_sizes[0] / 17;
    const int E = in_sizes[1] / 2;
    const int G = in_sizes[3] / 5;
    const int ET = E + N;

    float* ws = (float*)d_ws;
    size_t o = 0;
    float* xl1 = ws + o; o += (size_t)N * 128;
    float* xr1 = ws + o; o += (size_t)N * 128;
    float* h1  = ws + o; o += (size_t)N * 128;
    int* srcs = (int*)(ws + o); o += (size_t)ET;
    int* rowptr = (int*)(ws + o); o += (size_t)(N + 1);
    int* deg = (int*)(ws + o); o += (size_t)N;   // reused as cursor after scan
    int* part = (int*)(ws + o); o += 64;
    int* gb = (int*)(ws + o); o += (size_t)(G + 1);
    // layer-2 buffers alias the (dead) xl1 region: 3*N*32 <= N*128
    float* xl2 = xl1;
    float* xr2 = xl1 + (size_t)N * 32;
    float* h2  = xl1 + (size_t)2 * N * 32;

    const int NB = (N + SCH - 1) / SCH;
    const int eb = (ET + 255) / 256;

    // ---- CSR build (by dst) ----
    k_zero_i<<<256, 256, 0, stream>>>(deg, N);
    k_hist<<<eb, 256, 0, stream>>>(ei, E, ET, deg);
    k_scan1<<<NB, SCH, 0, stream>>>(deg, N, rowptr, part);
    k_scan2<<<1, 64, 0, stream>>>(part, NB);
    k_scan3<<<NB, SCH, 0, stream>>>(rowptr, part, N, deg);  // also zeroes cursor(=deg)
    k_fill<<<eb, 256, 0, stream>>>(ei, E, ET, rowptr, deg, srcs);

    // ---- layer 1 ----
    k_xform1<<<2048, 256, 0, stream>>>(x, Wl1, bl1, Wr1, br1, xl1, xr1, N);
    k_agg1<<<(N * 64 + 255) / 256, 256, 0, stream>>>(rowptr, srcs, xl1, xr1, att1, bias1, h1, N);

    // ---- layer 2 ----
    k_xform2<<<2048, 256, 0, stream>>>(h1, Wl2, bl2, Wr2, br2, xl2, xr2, N);
    k_agg2<<<(((N + 1) / 2) * 64 + 255) / 256, 256, 0, stream>>>(rowptr, srcs, xl2, xr2, att2, bias2, h2, N);

    // ---- pooling bounds + head ----
    k_bounds<<<1, 128, 0, stream>>>(batch, N, G, gb);
    k_head<<<G, 256, 0, stream>>>(h2, gb, obs, nf, ne,
                                  Wo1, bo1, Wo2, bo2, Wn, bn,
                                  Wf1, bf1, Wf2, bf2, Wf3, bf3,
                                  (float*)d_out);
}

// Round 3
// 337.690 us; speedup vs baseline: 5.7420x; 1.1790x over previous
//
#include <hip/hip_runtime.h>
#include <math.h>

#define CH 8

// ---------------- utility: zero ints ----------------
__global__ void k_zero_i(int* a, int n) {
    int i = blockIdx.x * blockDim.x + threadIdx.x;
    int s = gridDim.x * blockDim.x;
    for (; i < n; i += s) a[i] = 0;
}

// ---------------- CSR build ----------------
__global__ void k_hist(const int* __restrict__ ei, int E, int ET, int* __restrict__ deg) {
    int e = blockIdx.x * blockDim.x + threadIdx.x;
    if (e >= ET) return;
    int dst = (e < E) ? ei[E + e] : (e - E);
    atomicAdd(deg + dst, 1);
}

#define SCH 1024
__global__ void k_scan1(const int* __restrict__ deg, int N, int* __restrict__ rowptr,
                        int* __restrict__ part) {
    __shared__ int s[SCH];
    int b = blockIdx.x, t = threadIdx.x;
    int gi = b * SCH + t;
    s[t] = (gi < N) ? deg[gi] : 0;
    __syncthreads();
    for (int o = 1; o < SCH; o <<= 1) {
        int add = (t >= o) ? s[t - o] : 0;
        __syncthreads();
        s[t] += add;
        __syncthreads();
    }
    if (gi < N) rowptr[gi + 1] = s[t];
    if (t == SCH - 1) part[b] = s[t];
}

__global__ void k_scan3(int* __restrict__ rowptr, const int* __restrict__ part, int N,
                        int* __restrict__ cursor) {
    __shared__ int base;
    int b = blockIdx.x, t = threadIdx.x;
    if (t == 0) {
        int r = 0;
        for (int i = 0; i < b; i++) r += part[i];
        base = r;
    }
    __syncthreads();
    int gi = b * SCH + t;
    if (gi < N) {
        rowptr[gi + 1] += base;
        cursor[gi] = 0;
    }
    if (b == 0 && t == 0) rowptr[0] = 0;
}

__global__ void k_fill(const int* __restrict__ ei, int E, int ET,
                       const int* __restrict__ rowptr, int* __restrict__ cursor,
                       int* __restrict__ srcs) {
    int e = blockIdx.x * blockDim.x + threadIdx.x;
    if (e >= ET) return;
    int src = (e < E) ? ei[e] : (e - E);
    int dst = (e < E) ? ei[E + e] : (e - E);
    int slot = rowptr[dst] + atomicAdd(cursor + dst, 1);
    srcs[slot] = src;
}

// ---------------- layer 1 transform: 17 -> 128, pair-packed output ----------------
// xl/xr stored as float2: element [n*64 + d] = (dim d, dim d+64)
__global__ void k_xform1(const float* __restrict__ x,
                         const float* __restrict__ Wl, const float* __restrict__ bl,
                         const float* __restrict__ Wr, const float* __restrict__ br,
                         float2* __restrict__ xl, float2* __restrict__ xr, int N) {
    __shared__ float wl[17 * 128], wr[17 * 128], sbl[128], sbr[128];
    int t = threadIdx.x;  // 256
    for (int i = t; i < 17 * 128; i += 256) { wl[i] = Wl[i]; wr[i] = Wr[i]; }
    if (t < 128) { sbl[t] = bl[t]; sbr[t] = br[t]; }
    __syncthreads();
    int wid = (blockIdx.x * 256 + t) >> 6;
    int lane = t & 63;
    int nw = gridDim.x * 4;
    for (int n = wid; n < N; n += nw) {
        float xv[17];
#pragma unroll
        for (int k = 0; k < 17; k++) xv[k] = x[n * 17 + k];
        float a0 = sbl[lane], a1 = sbl[lane + 64];
        float b0 = sbr[lane], b1 = sbr[lane + 64];
#pragma unroll
        for (int k = 0; k < 17; k++) {
            float xk = xv[k];
            a0 += xk * wl[k * 128 + lane];
            a1 += xk * wl[k * 128 + 64 + lane];
            b0 += xk * wr[k * 128 + lane];
            b1 += xk * wr[k * 128 + 64 + lane];
        }
        xl[n * 64 + lane] = make_float2(a0, a1);
        xr[n * 64 + lane] = make_float2(b0, b1);
    }
}

// ---------------- layer 1 aggregate: one wave per dst, chunked online softmax ----------------
__global__ void k_agg1(const int* __restrict__ rowptr, const int* __restrict__ srcs,
                       const float2* __restrict__ xl, const float2* __restrict__ xr,
                       const float* __restrict__ att, const float* __restrict__ bias,
                       float* __restrict__ h1, int N) {
    int w = (blockIdx.x * blockDim.x + threadIdx.x) >> 6;
    int lane = threadIdx.x & 63;
    if (w >= N) return;
    float2 r = xr[w * 64 + lane];
    float a0 = att[lane], a1 = att[lane + 64];
    float m = -INFINITY, den = 0.f, acc0 = 0.f, acc1 = 0.f;
    int jb = rowptr[w], je = rowptr[w + 1];
    for (int j0 = jb; j0 < je; j0 += CH) {
        int s[CH];
        float l0[CH], l1[CH], p[CH];
#pragma unroll
        for (int c = 0; c < CH; c++) {
            int j = j0 + c;
            s[c] = (j < je) ? srcs[j] : 0;
        }
#pragma unroll
        for (int c = 0; c < CH; c++) {
            float2 l = xl[s[c] * 64 + lane];
            l0[c] = l.x; l1[c] = l.y;
        }
#pragma unroll
        for (int c = 0; c < CH; c++) {
            float v0 = l0[c] + r.x; v0 = (v0 > 0.f) ? v0 : 0.2f * v0;
            float v1 = l1[c] + r.y; v1 = (v1 > 0.f) ? v1 : 0.2f * v1;
            p[c] = v0 * a0 + v1 * a1;
        }
#pragma unroll
        for (int o = 32; o; o >>= 1) {
#pragma unroll
            for (int c = 0; c < CH; c++) p[c] += __shfl_xor(p[c], o);
        }
#pragma unroll
        for (int c = 0; c < CH; c++)
            if (j0 + c >= je) p[c] = -INFINITY;
        float cm = p[0];
#pragma unroll
        for (int c = 1; c < CH; c++) cm = fmaxf(cm, p[c]);
        if (cm > m) {
            float sc = __expf(m - cm);
            den *= sc; acc0 *= sc; acc1 *= sc; m = cm;
        }
#pragma unroll
        for (int c = 0; c < CH; c++) {
            float e = __expf(p[c] - m);
            den += e; acc0 += e * l0[c]; acc1 += e * l1[c];
        }
    }
    float inv = 1.f / (den + 1e-16f);
    float o0 = acc0 * inv + bias[lane];
    float o1 = acc1 * inv + bias[lane + 64];
    h1[w * 128 + lane] = (o0 > 0.f) ? o0 : expm1f(o0);
    h1[w * 128 + 64 + lane] = (o1 > 0.f) ? o1 : expm1f(o1);
}

// ---------------- layer 2 transform: 128 -> 32, weight-stationary ----------------
__global__ void k_xform2(const float* __restrict__ h,
                         const float* __restrict__ Wl, const float* __restrict__ bl,
                         const float* __restrict__ Wr, const float* __restrict__ br,
                         float* __restrict__ xl2, float* __restrict__ xr2, int N) {
    __shared__ float wl[128 * 32], wr[128 * 32], sb[64];
    int t = threadIdx.x;  // 256
    for (int i = t; i < 128 * 32; i += 256) { wl[i] = Wl[i]; wr[i] = Wr[i]; }
    if (t < 32) sb[t] = bl[t];
    else if (t < 64) sb[t] = br[t - 32];
    __syncthreads();
    int wid = (blockIdx.x * 256 + t) >> 6;
    int lane = t & 63;
    int half = lane >> 5, d = lane & 31;
    const float* w = half ? wr : wl;
    float* o = half ? xr2 : xl2;
    float bb = sb[half * 32 + d];
    int nw = gridDim.x * 4;
    for (int n = wid; n < N; n += nw) {
        const float* hr = h + n * 128;
        float a = bb;
#pragma unroll 8
        for (int k = 0; k < 128; k++) a += hr[k] * w[k * 32 + d];
        o[n * 32 + d] = a;
    }
}

// ---------------- layer 2 aggregate: 32-lane group per dst, chunked ----------------
__global__ void k_agg2(const int* __restrict__ rowptr, const int* __restrict__ srcs,
                       const float* __restrict__ xl, const float* __restrict__ xr,
                       const float* __restrict__ att, const float* __restrict__ bias,
                       float* __restrict__ h2, int N) {
    int node = (blockIdx.x * blockDim.x + threadIdx.x) >> 5;
    int d = threadIdx.x & 31;
    if (node >= N) return;
    float r = xr[node * 32 + d], a = att[d];
    float m = -INFINITY, den = 0.f, acc = 0.f;
    int jb = rowptr[node], je = rowptr[node + 1];
    for (int j0 = jb; j0 < je; j0 += CH) {
        int s[CH];
        float l[CH], p[CH];
#pragma unroll
        for (int c = 0; c < CH; c++) {
            int j = j0 + c;
            s[c] = (j < je) ? srcs[j] : 0;
        }
#pragma unroll
        for (int c = 0; c < CH; c++) l[c] = xl[s[c] * 32 + d];
#pragma unroll
        for (int c = 0; c < CH; c++) {
            float v = l[c] + r; v = (v > 0.f) ? v : 0.2f * v;
            p[c] = v * a;
        }
#pragma unroll
        for (int o = 16; o; o >>= 1) {
#pragma unroll
            for (int c = 0; c < CH; c++) p[c] += __shfl_xor(p[c], o, 32);
        }
#pragma unroll
        for (int c = 0; c < CH; c++)
            if (j0 + c >= je) p[c] = -INFINITY;
        float cm = p[0];
#pragma unroll
        for (int c = 1; c < CH; c++) cm = fmaxf(cm, p[c]);
        if (cm > m) {
            float sc = __expf(m - cm);
            den *= sc; acc *= sc; m = cm;
        }
#pragma unroll
        for (int c = 0; c < CH; c++) {
            float e = __expf(p[c] - m);
            den += e; acc += e * l[c];
        }
    }
    float ov = acc / (den + 1e-16f) + bias[d];
    h2[node * 32 + d] = (ov > 0.f) ? ov : expm1f(ov);
}

// ---------------- head: bounds + pool + encoders + fusion MLP ----------------
__global__ void k_head(const float* __restrict__ h2, const int* __restrict__ batch,
                       int N, int G,
                       const float* __restrict__ obs, const float* __restrict__ nf,
                       const float* __restrict__ ne,
                       const float* __restrict__ Wo1, const float* __restrict__ bo1,
                       const float* __restrict__ Wo2, const float* __restrict__ bo2,
                       const float* __restrict__ Wn, const float* __restrict__ bn,
                       const float* __restrict__ Wf1, const float* __restrict__ bf1,
                       const float* __restrict__ Wf2, const float* __restrict__ bf2,
                       const float* __restrict__ Wf3, const float* __restrict__ bf3,
                       float* __restrict__ out) {
    __shared__ float red[8][33];
    __shared__ float comb[45];
    __shared__ float ho[32];
    __shared__ float hh1[256];
    __shared__ float hh2[32];
    __shared__ int bounds[2];
    int g = blockIdx.x;
    int t = threadIdx.x;  // 256
    if (t < 2) {
        int target = g + t;
        if (target >= G) bounds[t] = N;
        else {
            int lo = 0, hi = N;
            while (lo < hi) {
                int mid = (lo + hi) >> 1;
                if (batch[mid] < target) lo = mid + 1; else hi = mid;
            }
            bounds[t] = lo;
        }
    }
    __syncthreads();
    int s0 = bounds[0], s1 = bounds[1];
    int d = t & 31, sub = t >> 5;
    float loc = 0.f;
    for (int n = s0 + sub; n < s1; n += 8) loc += h2[n * 32 + d];
    red[sub][d] = loc;
    __syncthreads();
    if (t < 32) {
        float sum = 0.f;
#pragma unroll
        for (int i = 0; i < 8; i++) sum += red[i][t];
        float c = (float)(s1 - s0);
        c = (c > 1.f) ? c : 1.f;
        comb[t] = sum / c;
        float a = bo1[t];
#pragma unroll
        for (int k = 0; k < 5; k++) a += obs[g * 5 + k] * Wo1[k * 32 + t];
        ho[t] = (a > 0.f) ? a : 0.f;
    }
    __syncthreads();
    if (t < 8) {
        float a = bo2[t];
#pragma unroll
        for (int k = 0; k < 32; k++) a += ho[k] * Wo2[k * 8 + t];
        comb[32 + t] = a;
    }
    if (t >= 8 && t < 12) {
        int dd = t - 8;
        comb[40 + dd] = nf[g] * Wn[dd] + bn[dd];
    }
    if (t == 12) comb[44] = ne[g];
    __syncthreads();
    {
        float a = bf1[t];
#pragma unroll
        for (int k = 0; k < 45; k++) a += comb[k] * Wf1[k * 256 + t];
        hh1[t] = (a > 0.f) ? a : 0.f;
    }
    __syncthreads();
    if (t < 32) {
        float a = bf2[t];
#pragma unroll
        for (int k = 0; k < 256; k++) a += hh1[k] * Wf2[k * 32 + t];
        hh2[t] = (a > 0.f) ? a : 0.f;
    }
    __syncthreads();
    if (t == 0) {
        float a = bf3[0];
#pragma unroll
        for (int k = 0; k < 32; k++) a += hh2[k] * Wf3[k];
        out[g] = ne[g] + a;
    }
}

extern "C" void kernel_launch(void* const* d_in, const int* in_sizes, int n_in,
                              void* d_out, int out_size, void* d_ws, size_t ws_size,
                              hipStream_t stream) {
    const float* x = (const float*)d_in[0];
    const int* ei = (const int*)d_in[1];
    const int* batch = (const int*)d_in[2];
    const float* obs = (const float*)d_in[3];
    const float* nf = (const float*)d_in[4];
    const float* ne = (const float*)d_in[5];
    const float* Wl1 = (const float*)d_in[6];
    const float* bl1 = (const float*)d_in[7];
    const float* Wr1 = (const float*)d_in[8];
    const float* br1 = (const float*)d_in[9];
    const float* att1 = (const float*)d_in[10];
    const float* bias1 = (const float*)d_in[11];
    const float* Wl2 = (const float*)d_in[12];
    const float* bl2 = (const float*)d_in[13];
    const float* Wr2 = (const float*)d_in[14];
    const float* br2 = (const float*)d_in[15];
    const float* att2 = (const float*)d_in[16];
    const float* bias2 = (const float*)d_in[17];
    const float* Wo1 = (const float*)d_in[18];
    const float* bo1 = (const float*)d_in[19];
    const float* Wo2 = (const float*)d_in[20];
    const float* bo2 = (const float*)d_in[21];
    const float* Wn = (const float*)d_in[22];
    const float* bn = (const float*)d_in[23];
    const float* Wf1 = (const float*)d_in[24];
    const float* bf1 = (const float*)d_in[25];
    const float* Wf2 = (const float*)d_in[26];
    const float* bf2 = (const float*)d_in[27];
    const float* Wf3 = (const float*)d_in[28];
    const float* bf3 = (const float*)d_in[29];

    const int N = in_sizes[0] / 17;
    const int E = in_sizes[1] / 2;
    const int G = in_sizes[3] / 5;
    const int ET = E + N;

    float* ws = (float*)d_ws;
    size_t o = 0;
    float* xl1 = ws + o; o += (size_t)N * 128;   // pair-packed float2[N*64]
    float* xr1 = ws + o; o += (size_t)N * 128;   // pair-packed
    float* h1  = ws + o; o += (size_t)N * 128;   // natural layout
    int* srcs = (int*)(ws + o); o += (size_t)ET;
    int* rowptr = (int*)(ws + o); o += (size_t)(N + 1);
    int* deg = (int*)(ws + o); o += (size_t)N;   // reused as cursor after scan
    int* part = (int*)(ws + o); o += 64;
    // layer-2 buffers alias the (dead) xl1 region: 3*N*32 <= N*128
    float* xl2 = xl1;
    float* xr2 = xl1 + (size_t)N * 32;
    float* h2  = xl1 + (size_t)2 * N * 32;

    const int NB = (N + SCH - 1) / SCH;
    const int eb = (ET + 255) / 256;

    // ---- CSR build (by dst) ----
    k_zero_i<<<256, 256, 0, stream>>>(deg, N);
    k_hist<<<eb, 256, 0, stream>>>(ei, E, ET, deg);
    k_scan1<<<NB, SCH, 0, stream>>>(deg, N, rowptr, part);
    k_scan3<<<NB, SCH, 0, stream>>>(rowptr, part, N, deg);  // adds partials, zeroes cursor
    k_fill<<<eb, 256, 0, stream>>>(ei, E, ET, rowptr, deg, srcs);

    // ---- layer 1 ----
    k_xform1<<<2048, 256, 0, stream>>>(x, Wl1, bl1, Wr1, br1,
                                       (float2*)xl1, (float2*)xr1, N);
    k_agg1<<<(N * 64 + 255) / 256, 256, 0, stream>>>(rowptr, srcs, (const float2*)xl1,
                                                     (const float2*)xr1, att1, bias1, h1, N);

    // ---- layer 2 ----
    k_xform2<<<2048, 256, 0, stream>>>(h1, Wl2, bl2, Wr2, br2, xl2, xr2, N);
    k_agg2<<<(N * 32 + 255) / 256, 256, 0, stream>>>(rowptr, srcs, xl2, xr2, att2, bias2, h2, N);

    // ---- head (bounds fused) ----
    k_head<<<G, 256, 0, stream>>>(h2, batch, N, G, obs, nf, ne,
                                  Wo1, bo1, Wo2, bo2, Wn, bn,
                                  Wf1, bf1, Wf2, bf2, Wf3, bf3,
                                  (float*)d_out);
}

// Round 4
// 325.420 us; speedup vs baseline: 5.9585x; 1.0377x over previous
//
#include <hip/hip_runtime.h>
#include <math.h>

#define CH 8
#define DEV __device__ __forceinline__

// ---- cross-lane sums off the LDS pipe: DPP row_ror for 16-lane rows ----
template<int CTRL>
DEV float dpp_add(float x) {
    int y = __builtin_amdgcn_update_dpp(0, __float_as_int(x), CTRL, 0xf, 0xf, true);
    return x + __int_as_float(y);
}
DEV float sum16(float p) {
    p = dpp_add<0x121>(p);  // row_ror:1
    p = dpp_add<0x122>(p);  // row_ror:2
    p = dpp_add<0x124>(p);  // row_ror:4
    p = dpp_add<0x128>(p);  // row_ror:8  -> all 16 lanes of each row hold row-sum
    return p;
}
DEV float sum32(float p) {  // sum within each 32-lane group, result in all lanes
    p = sum16(p);
    int t = __builtin_amdgcn_ds_swizzle(__float_as_int(p), 0x401f);  // xor lane^16
    return p + __int_as_float(t);
}
DEV float sum64(float p) {  // full-wave sum, result in all lanes
    p = sum32(p);
    return p + __shfl_xor(p, 32);
}

// ---------------- utility: zero ints ----------------
__global__ void k_zero_i(int* a, int n) {
    int i = blockIdx.x * blockDim.x + threadIdx.x;
    int s = gridDim.x * blockDim.x;
    for (; i < n; i += s) a[i] = 0;
}

// ---------------- CSR build ----------------
__global__ void k_hist(const int* __restrict__ ei, int E, int ET, int* __restrict__ deg) {
    int e = blockIdx.x * blockDim.x + threadIdx.x;
    if (e >= ET) return;
    int dst = (e < E) ? ei[E + e] : (e - E);
    atomicAdd(deg + dst, 1);
}

#define SCH 1024
__global__ void k_scan1(const int* __restrict__ deg, int N, int* __restrict__ rowptr,
                        int* __restrict__ part) {
    __shared__ int s[SCH];
    int b = blockIdx.x, t = threadIdx.x;
    int gi = b * SCH + t;
    s[t] = (gi < N) ? deg[gi] : 0;
    __syncthreads();
    for (int o = 1; o < SCH; o <<= 1) {
        int add = (t >= o) ? s[t - o] : 0;
        __syncthreads();
        s[t] += add;
        __syncthreads();
    }
    if (gi < N) rowptr[gi + 1] = s[t];
    if (t == SCH - 1) part[b] = s[t];
}

__global__ void k_scan3(int* __restrict__ rowptr, const int* __restrict__ part, int N,
                        int* __restrict__ cursor) {
    __shared__ int base;
    int b = blockIdx.x, t = threadIdx.x;
    if (t == 0) {
        int r = 0;
        for (int i = 0; i < b; i++) r += part[i];
        base = r;
    }
    __syncthreads();
    int gi = b * SCH + t;
    if (gi < N) {
        rowptr[gi + 1] += base;
        cursor[gi] = 0;
    }
    if (b == 0 && t == 0) rowptr[0] = 0;
}

__global__ void k_fill(const int* __restrict__ ei, int E, int ET,
                       const int* __restrict__ rowptr, int* __restrict__ cursor,
                       int* __restrict__ srcs) {
    int e = blockIdx.x * blockDim.x + threadIdx.x;
    if (e >= ET) return;
    int src = (e < E) ? ei[e] : (e - E);
    int dst = (e < E) ? ei[E + e] : (e - E);
    int slot = rowptr[dst] + atomicAdd(cursor + dst, 1);
    srcs[slot] = src;
}

// ---------------- layer 1 transform: 17 -> 128, pair-packed output ----------------
// xl/xr stored as float2: element [n*64 + d] = (dim d, dim d+64)
__global__ void k_xform1(const float* __restrict__ x,
                         const float* __restrict__ Wl, const float* __restrict__ bl,
                         const float* __restrict__ Wr, const float* __restrict__ br,
                         float2* __restrict__ xl, float2* __restrict__ xr, int N) {
    __shared__ float wl[17 * 128], wr[17 * 128], sbl[128], sbr[128];
    int t = threadIdx.x;  // 256
    for (int i = t; i < 17 * 128; i += 256) { wl[i] = Wl[i]; wr[i] = Wr[i]; }
    if (t < 128) { sbl[t] = bl[t]; sbr[t] = br[t]; }
    __syncthreads();
    int wid = (blockIdx.x * 256 + t) >> 6;
    int lane = t & 63;
    int nw = gridDim.x * 4;
    for (int n = wid; n < N; n += nw) {
        float xv[17];
#pragma unroll
        for (int k = 0; k < 17; k++) xv[k] = x[n * 17 + k];
        float a0 = sbl[lane], a1 = sbl[lane + 64];
        float b0 = sbr[lane], b1 = sbr[lane + 64];
#pragma unroll
        for (int k = 0; k < 17; k++) {
            float xk = xv[k];
            a0 += xk * wl[k * 128 + lane];
            a1 += xk * wl[k * 128 + 64 + lane];
            b0 += xk * wr[k * 128 + lane];
            b1 += xk * wr[k * 128 + 64 + lane];
        }
        xl[n * 64 + lane] = make_float2(a0, a1);
        xr[n * 64 + lane] = make_float2(b0, b1);
    }
}

// ---------------- layer 1 aggregate: one wave per dst, chunked online softmax ----------------
__global__ void k_agg1(const int* __restrict__ rowptr, const int* __restrict__ srcs,
                       const float2* __restrict__ xl, const float2* __restrict__ xr,
                       const float* __restrict__ att, const float* __restrict__ bias,
                       float* __restrict__ h1, int N) {
    int w = (blockIdx.x * blockDim.x + threadIdx.x) >> 6;
    int lane = threadIdx.x & 63;
    if (w >= N) return;
    float2 r = xr[w * 64 + lane];
    float a0 = att[lane], a1 = att[lane + 64];
    float m = -INFINITY, den = 0.f, acc0 = 0.f, acc1 = 0.f;
    int jb = rowptr[w], je = rowptr[w + 1];
    for (int j0 = jb; j0 < je; j0 += CH) {
        int s[CH];
        float l0[CH], l1[CH], p[CH];
#pragma unroll
        for (int c = 0; c < CH; c++) {
            int j = j0 + c;
            s[c] = (j < je) ? srcs[j] : 0;
        }
#pragma unroll
        for (int c = 0; c < CH; c++) {
            float2 l = xl[s[c] * 64 + lane];
            l0[c] = l.x; l1[c] = l.y;
        }
#pragma unroll
        for (int c = 0; c < CH; c++) {
            float v0 = l0[c] + r.x; v0 = (v0 > 0.f) ? v0 : 0.2f * v0;
            float v1 = l1[c] + r.y; v1 = (v1 > 0.f) ? v1 : 0.2f * v1;
            p[c] = v0 * a0 + v1 * a1;
        }
#pragma unroll
        for (int c = 0; c < CH; c++) p[c] = sum64(p[c]);
#pragma unroll
        for (int c = 0; c < CH; c++)
            if (j0 + c >= je) p[c] = -INFINITY;
        float cm = p[0];
#pragma unroll
        for (int c = 1; c < CH; c++) cm = fmaxf(cm, p[c]);
        if (cm > m) {
            float sc = __expf(m - cm);
            den *= sc; acc0 *= sc; acc1 *= sc; m = cm;
        }
#pragma unroll
        for (int c = 0; c < CH; c++) {
            float e = __expf(p[c] - m);
            den += e; acc0 += e * l0[c]; acc1 += e * l1[c];
        }
    }
    float inv = 1.f / (den + 1e-16f);
    float o0 = acc0 * inv + bias[lane];
    float o1 = acc1 * inv + bias[lane + 64];
    h1[w * 128 + lane] = (o0 > 0.f) ? o0 : expm1f(o0);
    h1[w * 128 + 64 + lane] = (o1 > 0.f) ? o1 : expm1f(o1);
}

// ---------------- layer 2 transform: 128 -> 32, weight-stationary ----------------
__global__ void k_xform2(const float* __restrict__ h,
                         const float* __restrict__ Wl, const float* __restrict__ bl,
                         const float* __restrict__ Wr, const float* __restrict__ br,
                         float* __restrict__ xl2, float* __restrict__ xr2, int N) {
    __shared__ float wl[128 * 32], wr[128 * 32], sb[64];
    int t = threadIdx.x;  // 256
    for (int i = t; i < 128 * 32; i += 256) { wl[i] = Wl[i]; wr[i] = Wr[i]; }
    if (t < 32) sb[t] = bl[t];
    else if (t < 64) sb[t] = br[t - 32];
    __syncthreads();
    int wid = (blockIdx.x * 256 + t) >> 6;
    int lane = t & 63;
    int half = lane >> 5, d = lane & 31;
    const float* w = half ? wr : wl;
    float* o = half ? xr2 : xl2;
    float bb = sb[half * 32 + d];
    int nw = gridDim.x * 4;
    for (int n = wid; n < N; n += nw) {
        const float* hr = h + n * 128;
        float a = bb;
#pragma unroll 8
        for (int k = 0; k < 128; k++) a += hr[k] * w[k * 32 + d];
        o[n * 32 + d] = a;
    }
}

// ---------------- layer 2 aggregate: 32-lane group per dst, chunked ----------------
__global__ void k_agg2(const int* __restrict__ rowptr, const int* __restrict__ srcs,
                       const float* __restrict__ xl, const float* __restrict__ xr,
                       const float* __restrict__ att, const float* __restrict__ bias,
                       float* __restrict__ h2, int N) {
    int node = (blockIdx.x * blockDim.x + threadIdx.x) >> 5;
    int d = threadIdx.x & 31;
    if (node >= N) return;
    float r = xr[node * 32 + d], a = att[d];
    float m = -INFINITY, den = 0.f, acc = 0.f;
    int jb = rowptr[node], je = rowptr[node + 1];
    for (int j0 = jb; j0 < je; j0 += CH) {
        int s[CH];
        float l[CH], p[CH];
#pragma unroll
        for (int c = 0; c < CH; c++) {
            int j = j0 + c;
            s[c] = (j < je) ? srcs[j] : 0;
        }
#pragma unroll
        for (int c = 0; c < CH; c++) l[c] = xl[s[c] * 32 + d];
#pragma unroll
        for (int c = 0; c < CH; c++) {
            float v = l[c] + r; v = (v > 0.f) ? v : 0.2f * v;
            p[c] = v * a;
        }
#pragma unroll
        for (int c = 0; c < CH; c++) p[c] = sum32(p[c]);
#pragma unroll
        for (int c = 0; c < CH; c++)
            if (j0 + c >= je) p[c] = -INFINITY;
        float cm = p[0];
#pragma unroll
        for (int c = 1; c < CH; c++) cm = fmaxf(cm, p[c]);
        if (cm > m) {
            float sc = __expf(m - cm);
            den *= sc; acc *= sc; m = cm;
        }
#pragma unroll
        for (int c = 0; c < CH; c++) {
            float e = __expf(p[c] - m);
            den += e; acc += e * l[c];
        }
    }
    float ov = acc / (den + 1e-16f) + bias[d];
    h2[node * 32 + d] = (ov > 0.f) ? ov : expm1f(ov);
}

// ---------------- head: bounds + pool + encoders + fusion MLP ----------------
__global__ void k_head(const float* __restrict__ h2, const int* __restrict__ batch,
                       int N, int G,
                       const float* __restrict__ obs, const float* __restrict__ nf,
                       const float* __restrict__ ne,
                       const float* __restrict__ Wo1, const float* __restrict__ bo1,
                       const float* __restrict__ Wo2, const float* __restrict__ bo2,
                       const float* __restrict__ Wn, const float* __restrict__ bn,
                       const float* __restrict__ Wf1, const float* __restrict__ bf1,
                       const float* __restrict__ Wf2, const float* __restrict__ bf2,
                       const float* __restrict__ Wf3, const float* __restrict__ bf3,
                       float* __restrict__ out) {
    __shared__ float red[8][33];
    __shared__ float comb[45];
    __shared__ float ho[32];
    __shared__ float hh1[256];
    __shared__ float hh2[32];
    __shared__ int bounds[2];
    int g = blockIdx.x;
    int t = threadIdx.x;  // 256
    if (t < 2) {
        int target = g + t;
        if (target >= G) bounds[t] = N;
        else {
            int lo = 0, hi = N;
            while (lo < hi) {
                int mid = (lo + hi) >> 1;
                if (batch[mid] < target) lo = mid + 1; else hi = mid;
            }
            bounds[t] = lo;
        }
    }
    __syncthreads();
    int s0 = bounds[0], s1 = bounds[1];
    int d = t & 31, sub = t >> 5;
    float loc = 0.f;
    for (int n = s0 + sub; n < s1; n += 8) loc += h2[n * 32 + d];
    red[sub][d] = loc;
    __syncthreads();
    if (t < 32) {
        float sum = 0.f;
#pragma unroll
        for (int i = 0; i < 8; i++) sum += red[i][t];
        float c = (float)(s1 - s0);
        c = (c > 1.f) ? c : 1.f;
        comb[t] = sum / c;
        float a = bo1[t];
#pragma unroll
        for (int k = 0; k < 5; k++) a += obs[g * 5 + k] * Wo1[k * 32 + t];
        ho[t] = (a > 0.f) ? a : 0.f;
    }
    __syncthreads();
    if (t < 8) {
        float a = bo2[t];
#pragma unroll
        for (int k = 0; k < 32; k++) a += ho[k] * Wo2[k * 8 + t];
        comb[32 + t] = a;
    }
    if (t >= 8 && t < 12) {
        int dd = t - 8;
        comb[40 + dd] = nf[g] * Wn[dd] + bn[dd];
    }
    if (t == 12) comb[44] = ne[g];
    __syncthreads();
    {
        float a = bf1[t];
#pragma unroll
        for (int k = 0; k < 45; k++) a += comb[k] * Wf1[k * 256 + t];
        hh1[t] = (a > 0.f) ? a : 0.f;
    }
    __syncthreads();
    if (t < 32) {
        float a = bf2[t];
#pragma unroll
        for (int k = 0; k < 256; k++) a += hh1[k] * Wf2[k * 32 + t];
        hh2[t] = (a > 0.f) ? a : 0.f;
    }
    __syncthreads();
    if (t == 0) {
        float a = bf3[0];
#pragma unroll
        for (int k = 0; k < 32; k++) a += hh2[k] * Wf3[k];
        out[g] = ne[g] + a;
    }
}

extern "C" void kernel_launch(void* const* d_in, const int* in_sizes, int n_in,
                              void* d_out, int out_size, void* d_ws, size_t ws_size,
                              hipStream_t stream) {
    const float* x = (const float*)d_in[0];
    const int* ei = (const int*)d_in[1];
    const int* batch = (const int*)d_in[2];
    const float* obs = (const float*)d_in[3];
    const float* nf = (const float*)d_in[4];
    const float* ne = (const float*)d_in[5];
    const float* Wl1 = (const float*)d_in[6];
    const float* bl1 = (const float*)d_in[7];
    const float* Wr1 = (const float*)d_in[8];
    const float* br1 = (const float*)d_in[9];
    const float* att1 = (const float*)d_in[10];
    const float* bias1 = (const float*)d_in[11];
    const float* Wl2 = (const float*)d_in[12];
    const float* bl2 = (const float*)d_in[13];
    const float* Wr2 = (const float*)d_in[14];
    const float* br2 = (const float*)d_in[15];
    const float* att2 = (const float*)d_in[16];
    const float* bias2 = (const float*)d_in[17];
    const float* Wo1 = (const float*)d_in[18];
    const float* bo1 = (const float*)d_in[19];
    const float* Wo2 = (const float*)d_in[20];
    const float* bo2 = (const float*)d_in[21];
    const float* Wn = (const float*)d_in[22];
    const float* bn = (const float*)d_in[23];
    const float* Wf1 = (const float*)d_in[24];
    const float* bf1 = (const float*)d_in[25];
    const float* Wf2 = (const float*)d_in[26];
    const float* bf2 = (const float*)d_in[27];
    const float* Wf3 = (const float*)d_in[28];
    const float* bf3 = (const float*)d_in[29];

    const int N = in_sizes[0] / 17;
    const int E = in_sizes[1] / 2;
    const int G = in_sizes[3] / 5;
    const int ET = E + N;

    float* ws = (float*)d_ws;
    size_t o = 0;
    float* xl1 = ws + o; o += (size_t)N * 128;   // pair-packed float2[N*64]
    float* xr1 = ws + o; o += (size_t)N * 128;   // pair-packed
    float* h1  = ws + o; o += (size_t)N * 128;   // natural layout
    int* srcs = (int*)(ws + o); o += (size_t)ET;
    int* rowptr = (int*)(ws + o); o += (size_t)(N + 1);
    int* deg = (int*)(ws + o); o += (size_t)N;   // reused as cursor after scan
    int* part = (int*)(ws + o); o += 64;
    // layer-2 buffers alias the (dead) xl1 region: 3*N*32 <= N*128
    float* xl2 = xl1;
    float* xr2 = xl1 + (size_t)N * 32;
    float* h2  = xl1 + (size_t)2 * N * 32;

    const int NB = (N + SCH - 1) / SCH;
    const int eb = (ET + 255) / 256;

    // ---- CSR build (by dst) ----
    k_zero_i<<<256, 256, 0, stream>>>(deg, N);
    k_hist<<<eb, 256, 0, stream>>>(ei, E, ET, deg);
    k_scan1<<<NB, SCH, 0, stream>>>(deg, N, rowptr, part);
    k_scan3<<<NB, SCH, 0, stream>>>(rowptr, part, N, deg);  // adds partials, zeroes cursor
    k_fill<<<eb, 256, 0, stream>>>(ei, E, ET, rowptr, deg, srcs);

    // ---- layer 1 ----
    k_xform1<<<2048, 256, 0, stream>>>(x, Wl1, bl1, Wr1, br1,
                                       (float2*)xl1, (float2*)xr1, N);
    k_agg1<<<(N * 64 + 255) / 256, 256, 0, stream>>>(rowptr, srcs, (const float2*)xl1,
                                                     (const float2*)xr1, att1, bias1, h1, N);

    // ---- layer 2 ----
    k_xform2<<<2048, 256, 0, stream>>>(h1, Wl2, bl2, Wr2, br2, xl2, xr2, N);
    k_agg2<<<(N * 32 + 255) / 256, 256, 0, stream>>>(rowptr, srcs, xl2, xr2, att2, bias2, h2, N);

    // ---- head (bounds fused) ----
    k_head<<<G, 256, 0, stream>>>(h2, batch, N, G, obs, nf, ne,
                                  Wo1, bo1, Wo2, bo2, Wn, bn,
                                  Wf1, bf1, Wf2, bf2, Wf3, bf3,
                                  (float*)d_out);
}

// Round 5
// 309.055 us; speedup vs baseline: 6.2740x; 1.0530x over previous
//
#include <hip/hip_runtime.h>
#include <math.h>

#define DEV __device__ __forceinline__

// ---- cross-lane sums off the LDS pipe: DPP row_ror for 16-lane rows ----
template<int CTRL>
DEV float dpp_add(float x) {
    int y = __builtin_amdgcn_update_dpp(0, __float_as_int(x), CTRL, 0xf, 0xf, true);
    return x + __int_as_float(y);
}
DEV float sum16(float p) {
    p = dpp_add<0x121>(p);  // row_ror:1
    p = dpp_add<0x122>(p);  // row_ror:2
    p = dpp_add<0x124>(p);  // row_ror:4
    p = dpp_add<0x128>(p);  // row_ror:8  -> all 16 lanes of each row hold row-sum
    return p;
}
DEV float sum32(float p) {  // sum within each 32-lane group, result in all lanes
    p = sum16(p);
    int t = __builtin_amdgcn_ds_swizzle(__float_as_int(p), 0x401f);  // xor lane^16
    return p + __int_as_float(t);
}

// ---------------- utility: zero ints ----------------
__global__ void k_zero_i(int* a, int n) {
    int i = blockIdx.x * blockDim.x + threadIdx.x;
    int s = gridDim.x * blockDim.x;
    for (; i < n; i += s) a[i] = 0;
}

// ---------------- CSR build ----------------
__global__ void k_hist(const int* __restrict__ ei, int E, int ET, int* __restrict__ deg) {
    int e = blockIdx.x * blockDim.x + threadIdx.x;
    if (e >= ET) return;
    int dst = (e < E) ? ei[E + e] : (e - E);
    atomicAdd(deg + dst, 1);
}

#define SCH 1024
__global__ void k_scan1(const int* __restrict__ deg, int N, int* __restrict__ rowptr,
                        int* __restrict__ part) {
    __shared__ int s[SCH];
    int b = blockIdx.x, t = threadIdx.x;
    int gi = b * SCH + t;
    s[t] = (gi < N) ? deg[gi] : 0;
    __syncthreads();
    for (int o = 1; o < SCH; o <<= 1) {
        int add = (t >= o) ? s[t - o] : 0;
        __syncthreads();
        s[t] += add;
        __syncthreads();
    }
    if (gi < N) rowptr[gi + 1] = s[t];
    if (t == SCH - 1) part[b] = s[t];
}

__global__ void k_scan3(int* __restrict__ rowptr, const int* __restrict__ part, int N,
                        int* __restrict__ cursor) {
    __shared__ int base;
    int b = blockIdx.x, t = threadIdx.x;
    if (t == 0) {
        int r = 0;
        for (int i = 0; i < b; i++) r += part[i];
        base = r;
    }
    __syncthreads();
    int gi = b * SCH + t;
    if (gi < N) {
        rowptr[gi + 1] += base;
        cursor[gi] = 0;
    }
    if (b == 0 && t == 0) rowptr[0] = 0;
}

__global__ void k_fill(const int* __restrict__ ei, int E, int ET,
                       const int* __restrict__ rowptr, int* __restrict__ cursor,
                       int* __restrict__ srcs) {
    int e = blockIdx.x * blockDim.x + threadIdx.x;
    if (e >= ET) return;
    int src = (e < E) ? ei[e] : (e - E);
    int dst = (e < E) ? ei[E + e] : (e - E);
    int slot = rowptr[dst] + atomicAdd(cursor + dst, 1);
    srcs[slot] = src;
}

// ---------------- layer 1 transform: 17 -> 128, natural layout ----------------
__global__ void k_xform1(const float* __restrict__ x,
                         const float* __restrict__ Wl, const float* __restrict__ bl,
                         const float* __restrict__ Wr, const float* __restrict__ br,
                         float* __restrict__ xl, float* __restrict__ xr, int N) {
    __shared__ float wl[17 * 128], wr[17 * 128], sbl[128], sbr[128];
    int t = threadIdx.x;  // 256
    for (int i = t; i < 17 * 128; i += 256) { wl[i] = Wl[i]; wr[i] = Wr[i]; }
    if (t < 128) { sbl[t] = bl[t]; sbr[t] = br[t]; }
    __syncthreads();
    int wid = (blockIdx.x * 256 + t) >> 6;
    int lane = t & 63;
    int nw = gridDim.x * 4;
    for (int n = wid; n < N; n += nw) {
        float xv[17];
#pragma unroll
        for (int k = 0; k < 17; k++) xv[k] = x[n * 17 + k];
        float a0 = sbl[lane], a1 = sbl[lane + 64];
        float b0 = sbr[lane], b1 = sbr[lane + 64];
#pragma unroll
        for (int k = 0; k < 17; k++) {
            float xk = xv[k];
            a0 += xk * wl[k * 128 + lane];
            a1 += xk * wl[k * 128 + 64 + lane];
            b0 += xk * wr[k * 128 + lane];
            b1 += xk * wr[k * 128 + 64 + lane];
        }
        xl[n * 128 + lane] = a0; xl[n * 128 + 64 + lane] = a1;
        xr[n * 128 + lane] = b0; xr[n * 128 + 64 + lane] = b1;
    }
}

// ---------------- layer 1 aggregate: 32-lane group per dst node, float4 ----------------
#define CH1 4
__global__ void k_agg1(const int* __restrict__ rowptr, const int* __restrict__ srcs,
                       const float4* __restrict__ xl, const float4* __restrict__ xr,
                       const float* __restrict__ att, const float* __restrict__ bias,
                       float4* __restrict__ h1, int N) {
    int node = (blockIdx.x * blockDim.x + threadIdx.x) >> 5;
    int sub = threadIdx.x & 31;
    if (node >= N) return;
    float4 r = xr[node * 32 + sub];
    float4 a = reinterpret_cast<const float4*>(att)[sub];
    float m = -INFINITY, den = 0.f;
    float4 acc = make_float4(0.f, 0.f, 0.f, 0.f);
    int jb = rowptr[node], je = rowptr[node + 1];
    for (int j0 = jb; j0 < je; j0 += CH1) {
        int s[CH1];
        float4 l[CH1];
        float p[CH1];
#pragma unroll
        for (int c = 0; c < CH1; c++) {
            int j = j0 + c;
            s[c] = (j < je) ? srcs[j] : 0;
        }
#pragma unroll
        for (int c = 0; c < CH1; c++) l[c] = xl[s[c] * 32 + sub];
#pragma unroll
        for (int c = 0; c < CH1; c++) {
            float v0 = l[c].x + r.x; v0 = (v0 > 0.f) ? v0 : 0.2f * v0;
            float v1 = l[c].y + r.y; v1 = (v1 > 0.f) ? v1 : 0.2f * v1;
            float v2 = l[c].z + r.z; v2 = (v2 > 0.f) ? v2 : 0.2f * v2;
            float v3 = l[c].w + r.w; v3 = (v3 > 0.f) ? v3 : 0.2f * v3;
            p[c] = v0 * a.x + v1 * a.y + v2 * a.z + v3 * a.w;
        }
#pragma unroll
        for (int c = 0; c < CH1; c++) p[c] = sum32(p[c]);
#pragma unroll
        for (int c = 0; c < CH1; c++)
            if (j0 + c >= je) p[c] = -INFINITY;
        float cm = fmaxf(fmaxf(p[0], p[1]), fmaxf(p[2], p[3]));
        if (cm > m) {
            float sc = __expf(m - cm);
            den *= sc; acc.x *= sc; acc.y *= sc; acc.z *= sc; acc.w *= sc;
            m = cm;
        }
#pragma unroll
        for (int c = 0; c < CH1; c++) {
            float e = __expf(p[c] - m);
            den += e;
            acc.x += e * l[c].x; acc.y += e * l[c].y;
            acc.z += e * l[c].z; acc.w += e * l[c].w;
        }
    }
    float inv = 1.f / (den + 1e-16f);
    float4 b = reinterpret_cast<const float4*>(bias)[sub];
    float4 o;
    o.x = acc.x * inv + b.x; o.x = (o.x > 0.f) ? o.x : expm1f(o.x);
    o.y = acc.y * inv + b.y; o.y = (o.y > 0.f) ? o.y : expm1f(o.y);
    o.z = acc.z * inv + b.z; o.z = (o.z > 0.f) ? o.z : expm1f(o.z);
    o.w = acc.w * inv + b.w; o.w = (o.w > 0.f) ? o.w : expm1f(o.w);
    h1[node * 32 + sub] = o;
}

// ---------------- layer 2 transform: 128 -> 32, weight-stationary ----------------
__global__ void k_xform2(const float* __restrict__ h,
                         const float* __restrict__ Wl, const float* __restrict__ bl,
                         const float* __restrict__ Wr, const float* __restrict__ br,
                         float* __restrict__ xl2, float* __restrict__ xr2, int N) {
    __shared__ float wl[128 * 32], wr[128 * 32], sb[64];
    int t = threadIdx.x;  // 256
    for (int i = t; i < 128 * 32; i += 256) { wl[i] = Wl[i]; wr[i] = Wr[i]; }
    if (t < 32) sb[t] = bl[t];
    else if (t < 64) sb[t] = br[t - 32];
    __syncthreads();
    int wid = (blockIdx.x * 256 + t) >> 6;
    int lane = t & 63;
    int half = lane >> 5, d = lane & 31;
    const float* w = half ? wr : wl;
    float* o = half ? xr2 : xl2;
    float bb = sb[half * 32 + d];
    int nw = gridDim.x * 4;
    for (int n = wid; n < N; n += nw) {
        const float* hr = h + n * 128;
        float a = bb;
#pragma unroll 8
        for (int k = 0; k < 128; k++) a += hr[k] * w[k * 32 + d];
        o[n * 32 + d] = a;
    }
}

// ---------------- layer 2 aggregate: 16-lane group per dst node, float2 ----------------
#define CH2 4
__global__ void k_agg2(const int* __restrict__ rowptr, const int* __restrict__ srcs,
                       const float2* __restrict__ xl, const float2* __restrict__ xr,
                       const float* __restrict__ att, const float* __restrict__ bias,
                       float2* __restrict__ h2, int N) {
    int node = (blockIdx.x * blockDim.x + threadIdx.x) >> 4;
    int sub = threadIdx.x & 15;
    if (node >= N) return;
    float2 r = xr[node * 16 + sub];
    float2 a = reinterpret_cast<const float2*>(att)[sub];
    float m = -INFINITY, den = 0.f;
    float2 acc = make_float2(0.f, 0.f);
    int jb = rowptr[node], je = rowptr[node + 1];
    for (int j0 = jb; j0 < je; j0 += CH2) {
        int s[CH2];
        float2 l[CH2];
        float p[CH2];
#pragma unroll
        for (int c = 0; c < CH2; c++) {
            int j = j0 + c;
            s[c] = (j < je) ? srcs[j] : 0;
        }
#pragma unroll
        for (int c = 0; c < CH2; c++) l[c] = xl[s[c] * 16 + sub];
#pragma unroll
        for (int c = 0; c < CH2; c++) {
            float v0 = l[c].x + r.x; v0 = (v0 > 0.f) ? v0 : 0.2f * v0;
            float v1 = l[c].y + r.y; v1 = (v1 > 0.f) ? v1 : 0.2f * v1;
            p[c] = v0 * a.x + v1 * a.y;
        }
#pragma unroll
        for (int c = 0; c < CH2; c++) p[c] = sum16(p[c]);
#pragma unroll
        for (int c = 0; c < CH2; c++)
            if (j0 + c >= je) p[c] = -INFINITY;
        float cm = fmaxf(fmaxf(p[0], p[1]), fmaxf(p[2], p[3]));
        if (cm > m) {
            float sc = __expf(m - cm);
            den *= sc; acc.x *= sc; acc.y *= sc;
            m = cm;
        }
#pragma unroll
        for (int c = 0; c < CH2; c++) {
            float e = __expf(p[c] - m);
            den += e;
            acc.x += e * l[c].x; acc.y += e * l[c].y;
        }
    }
    float inv = 1.f / (den + 1e-16f);
    float2 b = reinterpret_cast<const float2*>(bias)[sub];
    float2 o;
    o.x = acc.x * inv + b.x; o.x = (o.x > 0.f) ? o.x : expm1f(o.x);
    o.y = acc.y * inv + b.y; o.y = (o.y > 0.f) ? o.y : expm1f(o.y);
    h2[node * 16 + sub] = o;
}

// ---------------- head: bounds + pool + encoders + fusion MLP ----------------
__global__ void k_head(const float* __restrict__ h2, const int* __restrict__ batch,
                       int N, int G,
                       const float* __restrict__ obs, const float* __restrict__ nf,
                       const float* __restrict__ ne,
                       const float* __restrict__ Wo1, const float* __restrict__ bo1,
                       const float* __restrict__ Wo2, const float* __restrict__ bo2,
                       const float* __restrict__ Wn, const float* __restrict__ bn,
                       const float* __restrict__ Wf1, const float* __restrict__ bf1,
                       const float* __restrict__ Wf2, const float* __restrict__ bf2,
                       const float* __restrict__ Wf3, const float* __restrict__ bf3,
                       float* __restrict__ out) {
    __shared__ float red[8][33];
    __shared__ float comb[45];
    __shared__ float ho[32];
    __shared__ float hh1[256];
    __shared__ float hh2[32];
    __shared__ int bounds[2];
    int g = blockIdx.x;
    int t = threadIdx.x;  // 256
    if (t < 2) {
        int target = g + t;
        if (target >= G) bounds[t] = N;
        else {
            int lo = 0, hi = N;
            while (lo < hi) {
                int mid = (lo + hi) >> 1;
                if (batch[mid] < target) lo = mid + 1; else hi = mid;
            }
            bounds[t] = lo;
        }
    }
    __syncthreads();
    int s0 = bounds[0], s1 = bounds[1];
    int d = t & 31, sub = t >> 5;
    float loc = 0.f;
    for (int n = s0 + sub; n < s1; n += 8) loc += h2[n * 32 + d];
    red[sub][d] = loc;
    __syncthreads();
    if (t < 32) {
        float sum = 0.f;
#pragma unroll
        for (int i = 0; i < 8; i++) sum += red[i][t];
        float c = (float)(s1 - s0);
        c = (c > 1.f) ? c : 1.f;
        comb[t] = sum / c;
        float a = bo1[t];
#pragma unroll
        for (int k = 0; k < 5; k++) a += obs[g * 5 + k] * Wo1[k * 32 + t];
        ho[t] = (a > 0.f) ? a : 0.f;
    }
    __syncthreads();
    if (t < 8) {
        float a = bo2[t];
#pragma unroll
        for (int k = 0; k < 32; k++) a += ho[k] * Wo2[k * 8 + t];
        comb[32 + t] = a;
    }
    if (t >= 8 && t < 12) {
        int dd = t - 8;
        comb[40 + dd] = nf[g] * Wn[dd] + bn[dd];
    }
    if (t == 12) comb[44] = ne[g];
    __syncthreads();
    {
        float a = bf1[t];
#pragma unroll
        for (int k = 0; k < 45; k++) a += comb[k] * Wf1[k * 256 + t];
        hh1[t] = (a > 0.f) ? a : 0.f;
    }
    __syncthreads();
    if (t < 32) {
        float a = bf2[t];
#pragma unroll
        for (int k = 0; k < 256; k++) a += hh1[k] * Wf2[k * 32 + t];
        hh2[t] = (a > 0.f) ? a : 0.f;
    }
    __syncthreads();
    if (t == 0) {
        float a = bf3[0];
#pragma unroll
        for (int k = 0; k < 32; k++) a += hh2[k] * Wf3[k];
        out[g] = ne[g] + a;
    }
}

extern "C" void kernel_launch(void* const* d_in, const int* in_sizes, int n_in,
                              void* d_out, int out_size, void* d_ws, size_t ws_size,
                              hipStream_t stream) {
    const float* x = (const float*)d_in[0];
    const int* ei = (const int*)d_in[1];
    const int* batch = (const int*)d_in[2];
    const float* obs = (const float*)d_in[3];
    const float* nf = (const float*)d_in[4];
    const float* ne = (const float*)d_in[5];
    const float* Wl1 = (const float*)d_in[6];
    const float* bl1 = (const float*)d_in[7];
    const float* Wr1 = (const float*)d_in[8];
    const float* br1 = (const float*)d_in[9];
    const float* att1 = (const float*)d_in[10];
    const float* bias1 = (const float*)d_in[11];
    const float* Wl2 = (const float*)d_in[12];
    const float* bl2 = (const float*)d_in[13];
    const float* Wr2 = (const float*)d_in[14];
    const float* br2 = (const float*)d_in[15];
    const float* att2 = (const float*)d_in[16];
    const float* bias2 = (const float*)d_in[17];
    const float* Wo1 = (const float*)d_in[18];
    const float* bo1 = (const float*)d_in[19];
    const float* Wo2 = (const float*)d_in[20];
    const float* bo2 = (const float*)d_in[21];
    const float* Wn = (const float*)d_in[22];
    const float* bn = (const float*)d_in[23];
    const float* Wf1 = (const float*)d_in[24];
    const float* bf1 = (const float*)d_in[25];
    const float* Wf2 = (const float*)d_in[26];
    const float* bf2 = (const float*)d_in[27];
    const float* Wf3 = (const float*)d_in[28];
    const float* bf3 = (const float*)d_in[29];

    const int N = in_sizes[0] / 17;
    const int E = in_sizes[1] / 2;
    const int G = in_sizes[3] / 5;
    const int ET = E + N;

    float* ws = (float*)d_ws;
    size_t o = 0;
    float* xl1 = ws + o; o += (size_t)N * 128;   // natural [N][128]
    float* xr1 = ws + o; o += (size_t)N * 128;   // natural
    float* h1  = ws + o; o += (size_t)N * 128;   // natural
    int* srcs = (int*)(ws + o); o += (size_t)ET;
    int* rowptr = (int*)(ws + o); o += (size_t)(N + 1);
    int* deg = (int*)(ws + o); o += (size_t)N;   // reused as cursor after scan
    int* part = (int*)(ws + o); o += 64;
    // layer-2 buffers alias the (dead) xl1 region: 3*N*32 <= N*128
    float* xl2 = xl1;
    float* xr2 = xl1 + (size_t)N * 32;
    float* h2  = xl1 + (size_t)2 * N * 32;

    const int NB = (N + SCH - 1) / SCH;
    const int eb = (ET + 255) / 256;

    // ---- CSR build (by dst) ----
    k_zero_i<<<256, 256, 0, stream>>>(deg, N);
    k_hist<<<eb, 256, 0, stream>>>(ei, E, ET, deg);
    k_scan1<<<NB, SCH, 0, stream>>>(deg, N, rowptr, part);
    k_scan3<<<NB, SCH, 0, stream>>>(rowptr, part, N, deg);  // adds partials, zeroes cursor
    k_fill<<<eb, 256, 0, stream>>>(ei, E, ET, rowptr, deg, srcs);

    // ---- layer 1 ----
    k_xform1<<<2048, 256, 0, stream>>>(x, Wl1, bl1, Wr1, br1, xl1, xr1, N);
    k_agg1<<<(N * 32 + 255) / 256, 256, 0, stream>>>(rowptr, srcs, (const float4*)xl1,
                                                     (const float4*)xr1, att1, bias1,
                                                     (float4*)h1, N);

    // ---- layer 2 ----
    k_xform2<<<2048, 256, 0, stream>>>(h1, Wl2, bl2, Wr2, br2, xl2, xr2, N);
    k_agg2<<<(N * 16 + 255) / 256, 256, 0, stream>>>(rowptr, srcs, (const float2*)xl2,
                                                     (const float2*)xr2, att2, bias2,
                                                     (float2*)h2, N);

    // ---- head (bounds fused) ----
    k_head<<<G, 256, 0, stream>>>(h2, batch, N, G, obs, nf, ne,
                                  Wo1, bo1, Wo2, bo2, Wn, bn,
                                  Wf1, bf1, Wf2, bf2, Wf3, bf3,
                                  (float*)d_out);
}

// Round 6
// 282.073 us; speedup vs baseline: 6.8742x; 1.0957x over previous
//
#include <hip/hip_runtime.h>
#include <math.h>

#define DEV __device__ __forceinline__

// ---- cross-lane sums off the LDS pipe: DPP row_ror for 16-lane rows ----
template<int CTRL>
DEV float dpp_add(float x) {
    int y = __builtin_amdgcn_update_dpp(0, __float_as_int(x), CTRL, 0xf, 0xf, true);
    return x + __int_as_float(y);
}
DEV float sum16(float p) {
    p = dpp_add<0x121>(p);  // row_ror:1
    p = dpp_add<0x122>(p);  // row_ror:2
    p = dpp_add<0x124>(p);  // row_ror:4
    p = dpp_add<0x128>(p);  // row_ror:8  -> all 16 lanes of each row hold row-sum
    return p;
}

// ---- bf16 pack/unpack (RNE) ----
DEV unsigned pack_bf16(float a, float b) {
    unsigned ua = __float_as_uint(a); ua = (ua + 0x7FFFu + ((ua >> 16) & 1u)) >> 16;
    unsigned ub = __float_as_uint(b); ub = (ub + 0x7FFFu + ((ub >> 16) & 1u)) >> 16;
    return ua | (ub << 16);
}
DEV void unpack_bf16(unsigned u, float& lo, float& hi) {
    lo = __uint_as_float(u << 16);
    hi = __uint_as_float(u & 0xFFFF0000u);
}
DEV float leaky(float v) { return fmaxf(v, 0.2f * v); }

// ---------------- utility: zero ints ----------------
__global__ void k_zero_i(int* a, int n) {
    int i = blockIdx.x * blockDim.x + threadIdx.x;
    int s = gridDim.x * blockDim.x;
    for (; i < n; i += s) a[i] = 0;
}

// ---------------- CSR build ----------------
__global__ void k_hist(const int* __restrict__ ei, int E, int ET, int* __restrict__ deg) {
    int e = blockIdx.x * blockDim.x + threadIdx.x;
    if (e >= ET) return;
    int dst = (e < E) ? ei[E + e] : (e - E);
    atomicAdd(deg + dst, 1);
}

#define SCH 1024
__global__ void k_scan1(const int* __restrict__ deg, int N, int* __restrict__ rowptr,
                        int* __restrict__ part) {
    __shared__ int s[SCH];
    int b = blockIdx.x, t = threadIdx.x;
    int gi = b * SCH + t;
    s[t] = (gi < N) ? deg[gi] : 0;
    __syncthreads();
    for (int o = 1; o < SCH; o <<= 1) {
        int add = (t >= o) ? s[t - o] : 0;
        __syncthreads();
        s[t] += add;
        __syncthreads();
    }
    if (gi < N) rowptr[gi + 1] = s[t];
    if (t == SCH - 1) part[b] = s[t];
}

__global__ void k_scan3(int* __restrict__ rowptr, const int* __restrict__ part, int N,
                        int* __restrict__ cursor) {
    __shared__ int base;
    int b = blockIdx.x, t = threadIdx.x;
    if (t == 0) {
        int r = 0;
        for (int i = 0; i < b; i++) r += part[i];
        base = r;
    }
    __syncthreads();
    int gi = b * SCH + t;
    if (gi < N) {
        rowptr[gi + 1] += base;
        cursor[gi] = 0;
    }
    if (b == 0 && t == 0) rowptr[0] = 0;
}

__global__ void k_fill(const int* __restrict__ ei, int E, int ET,
                       const int* __restrict__ rowptr, int* __restrict__ cursor,
                       int* __restrict__ srcs) {
    int e = blockIdx.x * blockDim.x + threadIdx.x;
    if (e >= ET) return;
    int src = (e < E) ? ei[e] : (e - E);
    int dst = (e < E) ? ei[E + e] : (e - E);
    int slot = rowptr[dst] + atomicAdd(cursor + dst, 1);
    srcs[slot] = src;
}

// ---------------- layer 1 transform: 17 -> 128, bf16-packed output ----------------
// xlb/xrb: row = 64 uints, uint l holds bf16 dims (2l, 2l+1)
__global__ void k_xform1(const float* __restrict__ x,
                         const float* __restrict__ Wl, const float* __restrict__ bl,
                         const float* __restrict__ Wr, const float* __restrict__ br,
                         unsigned* __restrict__ xlb, unsigned* __restrict__ xrb, int N) {
    __shared__ float wl[17 * 128], wr[17 * 128], sbl[128], sbr[128];
    int t = threadIdx.x;  // 256
    for (int i = t; i < 17 * 128; i += 256) { wl[i] = Wl[i]; wr[i] = Wr[i]; }
    if (t < 128) { sbl[t] = bl[t]; sbr[t] = br[t]; }
    __syncthreads();
    int wid = (blockIdx.x * 256 + t) >> 6;
    int lane = t & 63;
    int nw = gridDim.x * 4;
    for (int n = wid; n < N; n += nw) {
        float xv[17];
#pragma unroll
        for (int k = 0; k < 17; k++) xv[k] = x[n * 17 + k];
        float a0 = sbl[2 * lane], a1 = sbl[2 * lane + 1];
        float b0 = sbr[2 * lane], b1 = sbr[2 * lane + 1];
#pragma unroll
        for (int k = 0; k < 17; k++) {
            float xk = xv[k];
            a0 += xk * wl[k * 128 + 2 * lane];
            a1 += xk * wl[k * 128 + 2 * lane + 1];
            b0 += xk * wr[k * 128 + 2 * lane];
            b1 += xk * wr[k * 128 + 2 * lane + 1];
        }
        xlb[n * 64 + lane] = pack_bf16(a0, a1);
        xrb[n * 64 + lane] = pack_bf16(b0, b1);
    }
}

// ---------------- layer 1 aggregate: 16-lane group per dst, bf16 rows ----------------
#define CH1 4
__global__ void k_agg1(const int* __restrict__ rowptr, const int* __restrict__ srcs,
                       const uint4* __restrict__ xlb, const uint4* __restrict__ xrb,
                       const float* __restrict__ att, const float* __restrict__ bias,
                       float4* __restrict__ h1, int N) {
    int node = (blockIdx.x * blockDim.x + threadIdx.x) >> 4;
    int sub = threadIdx.x & 15;  // 16 lanes; lane covers dims [sub*8, sub*8+8)
    if (node >= N) return;
    float r[8];
    {
        uint4 rv = xrb[node * 16 + sub];
        unpack_bf16(rv.x, r[0], r[1]); unpack_bf16(rv.y, r[2], r[3]);
        unpack_bf16(rv.z, r[4], r[5]); unpack_bf16(rv.w, r[6], r[7]);
    }
    const float4* att4 = (const float4*)att;
    float4 aa = att4[sub * 2], ab = att4[sub * 2 + 1];
    float m = -INFINITY, den = 0.f;
    float acc[8] = {0.f, 0.f, 0.f, 0.f, 0.f, 0.f, 0.f, 0.f};
    int jb = rowptr[node], je = rowptr[node + 1];
    for (int j0 = jb; j0 < je; j0 += CH1) {
        int s[CH1];
        uint4 lv[CH1];
        float l[CH1][8];
        float p[CH1];
#pragma unroll
        for (int c = 0; c < CH1; c++) {
            int j = j0 + c;
            s[c] = (j < je) ? srcs[j] : 0;
        }
#pragma unroll
        for (int c = 0; c < CH1; c++) lv[c] = xlb[s[c] * 16 + sub];
#pragma unroll
        for (int c = 0; c < CH1; c++) {
            unpack_bf16(lv[c].x, l[c][0], l[c][1]);
            unpack_bf16(lv[c].y, l[c][2], l[c][3]);
            unpack_bf16(lv[c].z, l[c][4], l[c][5]);
            unpack_bf16(lv[c].w, l[c][6], l[c][7]);
        }
#pragma unroll
        for (int c = 0; c < CH1; c++) {
            float q = 0.f;
            q = fmaf(leaky(l[c][0] + r[0]), aa.x, q);
            q = fmaf(leaky(l[c][1] + r[1]), aa.y, q);
            q = fmaf(leaky(l[c][2] + r[2]), aa.z, q);
            q = fmaf(leaky(l[c][3] + r[3]), aa.w, q);
            q = fmaf(leaky(l[c][4] + r[4]), ab.x, q);
            q = fmaf(leaky(l[c][5] + r[5]), ab.y, q);
            q = fmaf(leaky(l[c][6] + r[6]), ab.z, q);
            q = fmaf(leaky(l[c][7] + r[7]), ab.w, q);
            p[c] = q;
        }
#pragma unroll
        for (int c = 0; c < CH1; c++) p[c] = sum16(p[c]);
#pragma unroll
        for (int c = 0; c < CH1; c++)
            if (j0 + c >= je) p[c] = -INFINITY;
        float cm = fmaxf(fmaxf(p[0], p[1]), fmaxf(p[2], p[3]));
        if (cm > m) {
            float sc = __expf(m - cm);
            den *= sc;
#pragma unroll
            for (int d = 0; d < 8; d++) acc[d] *= sc;
            m = cm;
        }
#pragma unroll
        for (int c = 0; c < CH1; c++) {
            float e = __expf(p[c] - m);
            den += e;
#pragma unroll
            for (int d = 0; d < 8; d++) acc[d] = fmaf(e, l[c][d], acc[d]);
        }
    }
    float inv = 1.f / (den + 1e-16f);
    const float4* bias4 = (const float4*)bias;
    float4 b0 = bias4[sub * 2], b1 = bias4[sub * 2 + 1];
    float4 o0, o1;
    o0.x = acc[0] * inv + b0.x; o0.x = (o0.x > 0.f) ? o0.x : expm1f(o0.x);
    o0.y = acc[1] * inv + b0.y; o0.y = (o0.y > 0.f) ? o0.y : expm1f(o0.y);
    o0.z = acc[2] * inv + b0.z; o0.z = (o0.z > 0.f) ? o0.z : expm1f(o0.z);
    o0.w = acc[3] * inv + b0.w; o0.w = (o0.w > 0.f) ? o0.w : expm1f(o0.w);
    o1.x = acc[4] * inv + b1.x; o1.x = (o1.x > 0.f) ? o1.x : expm1f(o1.x);
    o1.y = acc[5] * inv + b1.y; o1.y = (o1.y > 0.f) ? o1.y : expm1f(o1.y);
    o1.z = acc[6] * inv + b1.z; o1.z = (o1.z > 0.f) ? o1.z : expm1f(o1.z);
    o1.w = acc[7] * inv + b1.w; o1.w = (o1.w > 0.f) ? o1.w : expm1f(o1.w);
    h1[node * 32 + sub * 2] = o0;
    h1[node * 32 + sub * 2 + 1] = o1;
}

// ---------------- layer 2 transform: 128 -> 32, weight-stationary ----------------
__global__ void k_xform2(const float* __restrict__ h,
                         const float* __restrict__ Wl, const float* __restrict__ bl,
                         const float* __restrict__ Wr, const float* __restrict__ br,
                         float* __restrict__ xl2, float* __restrict__ xr2, int N) {
    __shared__ float wl[128 * 32], wr[128 * 32], sb[64];
    int t = threadIdx.x;  // 256
    for (int i = t; i < 128 * 32; i += 256) { wl[i] = Wl[i]; wr[i] = Wr[i]; }
    if (t < 32) sb[t] = bl[t];
    else if (t < 64) sb[t] = br[t - 32];
    __syncthreads();
    int wid = (blockIdx.x * 256 + t) >> 6;
    int lane = t & 63;
    int half = lane >> 5, d = lane & 31;
    const float* w = half ? wr : wl;
    float* o = half ? xr2 : xl2;
    float bb = sb[half * 32 + d];
    int nw = gridDim.x * 4;
    for (int n = wid; n < N; n += nw) {
        const float* hr = h + n * 128;
        float a = bb;
#pragma unroll 8
        for (int k = 0; k < 128; k++) a += hr[k] * w[k * 32 + d];
        o[n * 32 + d] = a;
    }
}

// ---------------- layer 2 aggregate: 16-lane group per dst node, float2 ----------------
#define CH2 4
__global__ void k_agg2(const int* __restrict__ rowptr, const int* __restrict__ srcs,
                       const float2* __restrict__ xl, const float2* __restrict__ xr,
                       const float* __restrict__ att, const float* __restrict__ bias,
                       float2* __restrict__ h2, int N) {
    int node = (blockIdx.x * blockDim.x + threadIdx.x) >> 4;
    int sub = threadIdx.x & 15;
    if (node >= N) return;
    float2 r = xr[node * 16 + sub];
    float2 a = reinterpret_cast<const float2*>(att)[sub];
    float m = -INFINITY, den = 0.f;
    float2 acc = make_float2(0.f, 0.f);
    int jb = rowptr[node], je = rowptr[node + 1];
    for (int j0 = jb; j0 < je; j0 += CH2) {
        int s[CH2];
        float2 l[CH2];
        float p[CH2];
#pragma unroll
        for (int c = 0; c < CH2; c++) {
            int j = j0 + c;
            s[c] = (j < je) ? srcs[j] : 0;
        }
#pragma unroll
        for (int c = 0; c < CH2; c++) l[c] = xl[s[c] * 16 + sub];
#pragma unroll
        for (int c = 0; c < CH2; c++) {
            float v0 = leaky(l[c].x + r.x);
            float v1 = leaky(l[c].y + r.y);
            p[c] = fmaf(v0, a.x, v1 * a.y);
        }
#pragma unroll
        for (int c = 0; c < CH2; c++) p[c] = sum16(p[c]);
#pragma unroll
        for (int c = 0; c < CH2; c++)
            if (j0 + c >= je) p[c] = -INFINITY;
        float cm = fmaxf(fmaxf(p[0], p[1]), fmaxf(p[2], p[3]));
        if (cm > m) {
            float sc = __expf(m - cm);
            den *= sc; acc.x *= sc; acc.y *= sc;
            m = cm;
        }
#pragma unroll
        for (int c = 0; c < CH2; c++) {
            float e = __expf(p[c] - m);
            den += e;
            acc.x = fmaf(e, l[c].x, acc.x);
            acc.y = fmaf(e, l[c].y, acc.y);
        }
    }
    float inv = 1.f / (den + 1e-16f);
    float2 b = reinterpret_cast<const float2*>(bias)[sub];
    float2 o;
    o.x = acc.x * inv + b.x; o.x = (o.x > 0.f) ? o.x : expm1f(o.x);
    o.y = acc.y * inv + b.y; o.y = (o.y > 0.f) ? o.y : expm1f(o.y);
    h2[node * 16 + sub] = o;
}

// ---------------- head: bounds + pool + encoders + fusion MLP ----------------
__global__ void k_head(const float* __restrict__ h2, const int* __restrict__ batch,
                       int N, int G,
                       const float* __restrict__ obs, const float* __restrict__ nf,
                       const float* __restrict__ ne,
                       const float* __restrict__ Wo1, const float* __restrict__ bo1,
                       const float* __restrict__ Wo2, const float* __restrict__ bo2,
                       const float* __restrict__ Wn, const float* __restrict__ bn,
                       const float* __restrict__ Wf1, const float* __restrict__ bf1,
                       const float* __restrict__ Wf2, const float* __restrict__ bf2,
                       const float* __restrict__ Wf3, const float* __restrict__ bf3,
                       float* __restrict__ out) {
    __shared__ float red[8][33];
    __shared__ float comb[45];
    __shared__ float ho[32];
    __shared__ float hh1[256];
    __shared__ float hh2[32];
    __shared__ int bounds[2];
    int g = blockIdx.x;
    int t = threadIdx.x;  // 256
    if (t < 2) {
        int target = g + t;
        if (target >= G) bounds[t] = N;
        else {
            int lo = 0, hi = N;
            while (lo < hi) {
                int mid = (lo + hi) >> 1;
                if (batch[mid] < target) lo = mid + 1; else hi = mid;
            }
            bounds[t] = lo;
        }
    }
    __syncthreads();
    int s0 = bounds[0], s1 = bounds[1];
    int d = t & 31, sub = t >> 5;
    float loc = 0.f;
    for (int n = s0 + sub; n < s1; n += 8) loc += h2[n * 32 + d];
    red[sub][d] = loc;
    __syncthreads();
    if (t < 32) {
        float sum = 0.f;
#pragma unroll
        for (int i = 0; i < 8; i++) sum += red[i][t];
        float c = (float)(s1 - s0);
        c = (c > 1.f) ? c : 1.f;
        comb[t] = sum / c;
        float a = bo1[t];
#pragma unroll
        for (int k = 0; k < 5; k++) a += obs[g * 5 + k] * Wo1[k * 32 + t];
        ho[t] = (a > 0.f) ? a : 0.f;
    }
    __syncthreads();
    if (t < 8) {
        float a = bo2[t];
#pragma unroll
        for (int k = 0; k < 32; k++) a += ho[k] * Wo2[k * 8 + t];
        comb[32 + t] = a;
    }
    if (t >= 8 && t < 12) {
        int dd = t - 8;
        comb[40 + dd] = nf[g] * Wn[dd] + bn[dd];
    }
    if (t == 12) comb[44] = ne[g];
    __syncthreads();
    {
        float a = bf1[t];
#pragma unroll
        for (int k = 0; k < 45; k++) a += comb[k] * Wf1[k * 256 + t];
        hh1[t] = (a > 0.f) ? a : 0.f;
    }
    __syncthreads();
    if (t < 32) {
        float a = bf2[t];
#pragma unroll
        for (int k = 0; k < 256; k++) a += hh1[k] * Wf2[k * 32 + t];
        hh2[t] = (a > 0.f) ? a : 0.f;
    }
    __syncthreads();
    if (t == 0) {
        float a = bf3[0];
#pragma unroll
        for (int k = 0; k < 32; k++) a += hh2[k] * Wf3[k];
        out[g] = ne[g] + a;
    }
}

extern "C" void kernel_launch(void* const* d_in, const int* in_sizes, int n_in,
                              void* d_out, int out_size, void* d_ws, size_t ws_size,
                              hipStream_t stream) {
    const float* x = (const float*)d_in[0];
    const int* ei = (const int*)d_in[1];
    const int* batch = (const int*)d_in[2];
    const float* obs = (const float*)d_in[3];
    const float* nf = (const float*)d_in[4];
    const float* ne = (const float*)d_in[5];
    const float* Wl1 = (const float*)d_in[6];
    const float* bl1 = (const float*)d_in[7];
    const float* Wr1 = (const float*)d_in[8];
    const float* br1 = (const float*)d_in[9];
    const float* att1 = (const float*)d_in[10];
    const float* bias1 = (const float*)d_in[11];
    const float* Wl2 = (const float*)d_in[12];
    const float* bl2 = (const float*)d_in[13];
    const float* Wr2 = (const float*)d_in[14];
    const float* br2 = (const float*)d_in[15];
    const float* att2 = (const float*)d_in[16];
    const float* bias2 = (const float*)d_in[17];
    const float* Wo1 = (const float*)d_in[18];
    const float* bo1 = (const float*)d_in[19];
    const float* Wo2 = (const float*)d_in[20];
    const float* bo2 = (const float*)d_in[21];
    const float* Wn = (const float*)d_in[22];
    const float* bn = (const float*)d_in[23];
    const float* Wf1 = (const float*)d_in[24];
    const float* bf1 = (const float*)d_in[25];
    const float* Wf2 = (const float*)d_in[26];
    const float* bf2 = (const float*)d_in[27];
    const float* Wf3 = (const float*)d_in[28];
    const float* bf3 = (const float*)d_in[29];

    const int N = in_sizes[0] / 17;
    const int E = in_sizes[1] / 2;
    const int G = in_sizes[3] / 5;
    const int ET = E + N;

    float* ws = (float*)d_ws;
    size_t o = 0;
    unsigned* xlb = (unsigned*)(ws + o); o += (size_t)N * 64;  // bf16 rows, 256 B
    unsigned* xrb = (unsigned*)(ws + o); o += (size_t)N * 64;
    float* h1  = ws + o; o += (size_t)N * 128;                 // natural f32
    int* srcs = (int*)(ws + o); o += (size_t)ET;
    int* rowptr = (int*)(ws + o); o += (size_t)(N + 1);
    int* deg = (int*)(ws + o); o += (size_t)N;   // reused as cursor after scan
    int* part = (int*)(ws + o); o += 64;
    // layer-2 buffers alias the (dead) xlb+xrb region: 3*N*32 = N*96 <= N*128
    float* l2base = (float*)xlb;
    float* xl2 = l2base;
    float* xr2 = l2base + (size_t)N * 32;
    float* h2  = l2base + (size_t)2 * N * 32;

    const int NB = (N + SCH - 1) / SCH;
    const int eb = (ET + 255) / 256;

    // ---- CSR build (by dst) ----
    k_zero_i<<<256, 256, 0, stream>>>(deg, N);
    k_hist<<<eb, 256, 0, stream>>>(ei, E, ET, deg);
    k_scan1<<<NB, SCH, 0, stream>>>(deg, N, rowptr, part);
    k_scan3<<<NB, SCH, 0, stream>>>(rowptr, part, N, deg);  // adds partials, zeroes cursor
    k_fill<<<eb, 256, 0, stream>>>(ei, E, ET, rowptr, deg, srcs);

    // ---- layer 1 ----
    k_xform1<<<2048, 256, 0, stream>>>(x, Wl1, bl1, Wr1, br1, xlb, xrb, N);
    k_agg1<<<(N * 16 + 255) / 256, 256, 0, stream>>>(rowptr, srcs, (const uint4*)xlb,
                                                     (const uint4*)xrb, att1, bias1,
                                                     (float4*)h1, N);

    // ---- layer 2 ----
    k_xform2<<<2048, 256, 0, stream>>>(h1, Wl2, bl2, Wr2, br2, xl2, xr2, N);
    k_agg2<<<(N * 16 + 255) / 256, 256, 0, stream>>>(rowptr, srcs, (const float2*)xl2,
                                                     (const float2*)xr2, att2, bias2,
                                                     (float2*)h2, N);

    // ---- head (bounds fused) ----
    k_head<<<G, 256, 0, stream>>>(h2, batch, N, G, obs, nf, ne,
                                  Wo1, bo1, Wo2, bo2, Wn, bn,
                                  Wf1, bf1, Wf2, bf2, Wf3, bf3,
                                  (float*)d_out);
}